// Round 8
// baseline (196.519 us; speedup 1.0000x reference)
//
#include <hip/hip_runtime.h>
#include <math.h>

// Problem dims (fixed by setup_inputs)
#define DD    512
#define CNUM  64
#define SHOTS 16
#define NSUP  1024
#define QNQ   2048
#define REGP  0.1f
#define XKS   4      // xmu split-K parts

typedef __attribute__((ext_vector_type(8))) short short8;   // 8 bf16 = 4 VGPRs
typedef __attribute__((ext_vector_type(4))) float f32x4;

// bf16 round-to-nearest-even, raw bits
__device__ __forceinline__ unsigned short f2bf(float f) {
  unsigned int u = __float_as_uint(f);
  unsigned int r = (u + 0x7fffu + ((u >> 16) & 1u)) >> 16;
  return (unsigned short)r;
}
__device__ __forceinline__ float bf2f(unsigned short h) {
  return __uint_as_float((unsigned int)h << 16);
}

// ---------------- workspace layout (in floats) ----------------
static constexpr size_t OFF_W     = 0;                       // 512*512
static constexpr size_t OFF_MU    = OFF_W     + 512*512;     // 64*512
static constexpr size_t OFF_Y     = OFF_MU    + 64*512;      // 3136*512
static constexpr size_t OFF_Z     = OFF_Y     + 3136*512;    // 2048
static constexpr size_t OFF_WM    = OFF_Z     + 3136;        // 512
static constexpr size_t OFF_CONST = OFF_WM    + 512;         // 16
static constexpr size_t OFF_RMAP  = OFF_CONST + 16;          // 1088 ints
static constexpr size_t OFF_ZG    = OFF_RMAP  + 1088;        // 1088
static constexpr size_t OFF_VMU   = OFF_ZG    + 1088;        // 1088
static constexpr size_t OFF_MUBMU = OFF_VMU   + 1088;        // 64
static constexpr size_t OFF_MUN   = OFF_MUBMU + 64;          // 64
static constexpr size_t OFF_MINV  = OFF_MUN   + 64;          // 64*289
static constexpr size_t OFF_BIAS  = OFF_MINV  + 64*289;      // 64
static constexpr size_t OFF_QNRM  = OFF_BIAS  + 64;          // 2048
static constexpr size_t OFF_YN    = OFF_QNRM  + 2048;        // 2048
static constexpr size_t OFF_XMU   = OFF_YN    + 2048;        // XKS*64*2048 ([p][c][q])
static constexpr size_t OFF_RG    = OFF_XMU   + (size_t)XKS*2048*64; // 1088*2048 (also trinv T)
static constexpr size_t OFF_P     = OFF_RG    + 1088*2048;   // 3136*1024 bf16 (Y split)
static constexpr size_t OFF_PX    = OFF_P     + 3136*512;    // 3136*1024 bf16 (X split)
static constexpr size_t OFF_PW    = OFF_PX    + 3136*512;    // 512*1024 bf16 (W split)
static constexpr size_t OFF_FLAGS = OFF_PW    + 512*1024/2;  // 8 ints (phase flags)

// consts: 0 kap, 1 scale, 2 common, 3 coef, 4 bias0, 5 jlast,
// 6 cmu_m, 7 cmu_x, 8 D*log(scale), 9 Jinv_last, 10 c_sm, 11 logdetB

// ---- device-scope producer/consumer flags (all blocks resident) ----
__device__ __forceinline__ void flag_signal(int* f) {
  __syncthreads();
  __builtin_amdgcn_fence(__ATOMIC_RELEASE, "agent");   // wb L2 (cross-XCD visibility)
  if (threadIdx.x == 0)
    __hip_atomic_fetch_add(f, 1, __ATOMIC_RELAXED, __HIP_MEMORY_SCOPE_AGENT);
}
__device__ __forceinline__ void flag_wait(int* f, int n) {
  if (threadIdx.x == 0) {
    while (__hip_atomic_load(f, __ATOMIC_RELAXED, __HIP_MEMORY_SCOPE_AGENT) < n)
      __builtin_amdgcn_s_sleep(2);
  }
  __syncthreads();
  __builtin_amdgcn_fence(__ATOMIC_ACQUIRE, "agent");   // inv L1/L2 before reads
}

// ---- PX staging for 4 global rows (Xq then Xs), one block of 256 ----
__device__ __forceinline__ void px_rows(const float* __restrict__ Xq,
    const float* __restrict__ Xs, unsigned short* __restrict__ PX, int r0) {
  int tid = threadIdx.x;
  int row = r0 + (tid >> 6), lane = tid & 63;
  const float* src = (row < QNQ) ? Xq + (size_t)row * DD
                                 : Xs + (size_t)(row - QNQ) * DD;
  size_t prow = (size_t)row * 1024;
  #pragma unroll
  for (int p = 0; p < 2; p++) {
    int col = lane * 8 + p * 4;
    float4 v = *(const float4*)(src + col);
    ushort4 hi, lo;
    hi.x = f2bf(v.x); lo.x = f2bf(v.x - bf2f(hi.x));
    hi.y = f2bf(v.y); lo.y = f2bf(v.y - bf2f(hi.y));
    hi.z = f2bf(v.z); lo.z = f2bf(v.z - bf2f(hi.z));
    hi.w = f2bf(v.w); lo.w = f2bf(v.w - bf2f(hi.w));
    *(ushort4*)(PX + prow + col) = hi;
    *(ushort4*)(PX + prow + 512 + col) = lo;
  }
}

#define PSTR 72   // LDS row stride in bf16 (144 B: 2-way banks = free)

// ---- shared Y-tile body (3-combo bf16-split MFMA, tri-skip) ----
__device__ __forceinline__ void y_tile(const unsigned short* __restrict__ PX,
    const unsigned short* __restrict__ PW, float* __restrict__ Y,
    unsigned short* __restrict__ Pm, unsigned short* ush, int mt, int nt) {
  unsigned short* AshH = ush;
  unsigned short* AshL = ush + 64 * PSTR;
  unsigned short* BshH = ush + 2 * 64 * PSTR;
  unsigned short* BshL = ush + 3 * 64 * PSTR;
  int tid = threadIdx.x;
  int bm = mt * 64, bn = nt * 64;
  int lane = tid & 63, wave = tid >> 6;
  int wr = wave >> 1, wc = wave & 1;
  int mrow = lane & 15, q = lane >> 4;
  f32x4 acc00 = {}, acc01 = {}, acc10 = {}, acc11 = {};
  int kchunks = nt + 1;   // W lower-triangular: k < bn+64
  for (int it = 0; it < kchunks; it++) {
    int kc = it * 64;
    #pragma unroll
    for (int p = 0; p < 2; p++) {
      int idx = tid + 256 * p;
      int row = idx >> 3, c8 = (idx & 7) * 8;
      *(short8*)&AshH[row * PSTR + c8] =
          *(const short8*)(PX + (size_t)(bm + row) * 1024 + kc + c8);
      *(short8*)&AshL[row * PSTR + c8] =
          *(const short8*)(PX + (size_t)(bm + row) * 1024 + 512 + kc + c8);
      *(short8*)&BshH[row * PSTR + c8] =
          *(const short8*)(PW + (size_t)(bn + row) * 1024 + kc + c8);
      *(short8*)&BshL[row * PSTR + c8] =
          *(const short8*)(PW + (size_t)(bn + row) * 1024 + 512 + kc + c8);
    }
    __syncthreads();
    #pragma unroll
    for (int ks = 0; ks < 2; ks++) {
      int ko = ks * 32 + q * 8;
      short8 ah0 = *(const short8*)&AshH[(wr * 32 + mrow) * PSTR + ko];
      short8 ah1 = *(const short8*)&AshH[(wr * 32 + 16 + mrow) * PSTR + ko];
      short8 al0 = *(const short8*)&AshL[(wr * 32 + mrow) * PSTR + ko];
      short8 al1 = *(const short8*)&AshL[(wr * 32 + 16 + mrow) * PSTR + ko];
      short8 bh0 = *(const short8*)&BshH[(wc * 32 + mrow) * PSTR + ko];
      short8 bh1 = *(const short8*)&BshH[(wc * 32 + 16 + mrow) * PSTR + ko];
      short8 bl0 = *(const short8*)&BshL[(wc * 32 + mrow) * PSTR + ko];
      short8 bl1 = *(const short8*)&BshL[(wc * 32 + 16 + mrow) * PSTR + ko];
      acc00 = __builtin_amdgcn_mfma_f32_16x16x32_bf16(ah0, bh0, acc00, 0, 0, 0);
      acc00 = __builtin_amdgcn_mfma_f32_16x16x32_bf16(ah0, bl0, acc00, 0, 0, 0);
      acc00 = __builtin_amdgcn_mfma_f32_16x16x32_bf16(al0, bh0, acc00, 0, 0, 0);
      acc01 = __builtin_amdgcn_mfma_f32_16x16x32_bf16(ah0, bh1, acc01, 0, 0, 0);
      acc01 = __builtin_amdgcn_mfma_f32_16x16x32_bf16(ah0, bl1, acc01, 0, 0, 0);
      acc01 = __builtin_amdgcn_mfma_f32_16x16x32_bf16(al0, bh1, acc01, 0, 0, 0);
      acc10 = __builtin_amdgcn_mfma_f32_16x16x32_bf16(ah1, bh0, acc10, 0, 0, 0);
      acc10 = __builtin_amdgcn_mfma_f32_16x16x32_bf16(ah1, bl0, acc10, 0, 0, 0);
      acc10 = __builtin_amdgcn_mfma_f32_16x16x32_bf16(al1, bh0, acc10, 0, 0, 0);
      acc11 = __builtin_amdgcn_mfma_f32_16x16x32_bf16(ah1, bh1, acc11, 0, 0, 0);
      acc11 = __builtin_amdgcn_mfma_f32_16x16x32_bf16(ah1, bl1, acc11, 0, 0, 0);
      acc11 = __builtin_amdgcn_mfma_f32_16x16x32_bf16(al1, bh1, acc11, 0, 0, 0);
    }
    __syncthreads();
  }
  #pragma unroll
  for (int r = 0; r < 4; r++) {
    int row0 = bm + wr * 32 + q * 4 + r;
    int row1 = row0 + 16;
    int col0 = bn + wc * 32 + mrow;
    float vv[4] = {acc00[r], acc01[r], acc10[r], acc11[r]};
    int rows[4] = {row0, row0, row1, row1};
    int cols[4] = {col0, col0 + 16, col0, col0 + 16};
    #pragma unroll
    for (int e = 0; e < 4; e++) {
      Y[(size_t)rows[e] * DD + cols[e]] = vv[e];
      unsigned short h = f2bf(vv[e]), l = f2bf(vv[e] - bf2f(h));
      Pm[(size_t)rows[e] * 1024 + cols[e]] = h;
      Pm[(size_t)rows[e] * 1024 + 512 + cols[e]] = l;
    }
  }
}

// ---- wm rows: wm[row] = W[row, 0..row] . m (4 rows per block) ----
__device__ __forceinline__ void wm_rows(const float* __restrict__ W,
    const float* __restrict__ m, float* __restrict__ wm, int r0) {
  int tid = threadIdx.x;
  int wave = tid >> 6, lane = tid & 63;
  int row = r0 + wave;
  float s = 0.0f;
  for (int j = lane; j <= row; j += 64) s += W[(size_t)row * DD + j] * m[j];
  for (int off = 32; off > 0; off >>= 1) s += __shfl_down(s, off);
  if (lane == 0) wm[row] = s;
}

// ============ F1: diag-inv(+PW), consts+flags, mu/mun/rowmap(+PX), px rows 0..1023 ============
__global__ __launch_bounds__(256) void f_init(const float* tdiag, const float* tlow,
    const float* kappa, const float* nu, const int* labels, const float* Xs,
    const float* Xq, const float* m, float* W, float* cst,
    int* rowmap, float* mu, float* mun,
    unsigned short* PX, unsigned short* PW, int* flags) {
  __shared__ float sh[2 * 64 * 68 + 32 * 33];   // Ld | Wd | tsh = 39 KB
  __shared__ int sidx[SHOTS];
  int b = blockIdx.x, tid = threadIdx.x;
  if (b < 8) {
    // diag 64x64 inverse via blocked 16->32->64 (critical path: dispatch first)
    int jb = b;
    float* Ld = sh;                   // [64][68]
    float* Wd = sh + 64 * 68;         // [64][68]
    float* tsh = sh + 2 * 64 * 68;    // [32][33]
    for (int t = tid; t < 4096; t += 256) {
      int r = t >> 6, c = t & 63;
      int gr = jb * 64 + r;
      float v = (r == c) ? fabsf(tdiag[gr])
              : (r > c ? tlow[(size_t)gr * DD + jb * 64 + c] : 0.0f);
      Ld[r * 68 + c] = v;
      Wd[r * 68 + c] = 0.0f;
    }
    __syncthreads();
    if (tid < 64) {
      // 16x16 base inverse, column t of sub-block s — register chain
      int s = tid >> 4, t = tid & 15;
      int r0 = s * 16;
      float wreg[16];
      #pragma unroll
      for (int i = 0; i < 16; i++) {
        float w = (i == t) ? 1.0f : 0.0f;
        #pragma unroll
        for (int k = 0; k < 16; k++)
          if (k < i) w -= Ld[(r0 + i) * 68 + r0 + k] * wreg[k];
        wreg[i] = w / Ld[(r0 + i) * 68 + r0 + i];
      }
      #pragma unroll
      for (int i = 0; i < 16; i++) Wd[(r0 + i) * 68 + r0 + t] = wreg[i];
    }
    __syncthreads();
    for (int g2 = 0; g2 < 2; g2++) {
      int r0 = g2 * 32 + 16, c0 = g2 * 32;
      int rr = tid >> 4, cc = tid & 15;
      float t_ = 0.0f;
      #pragma unroll
      for (int k = 0; k < 16; k++)
        t_ += Ld[(r0 + rr) * 68 + c0 + k] * Wd[(c0 + k) * 68 + c0 + cc];
      tsh[rr * 33 + cc] = t_;
      __syncthreads();
      float x = 0.0f;
      #pragma unroll
      for (int k = 0; k < 16; k++)
        x -= Wd[(r0 + rr) * 68 + r0 + k] * tsh[k * 33 + cc];
      Wd[(r0 + rr) * 68 + c0 + cc] = x;
      __syncthreads();
    }
    {
      int rr = tid >> 6, cc = tid & 63;
      #pragma unroll
      for (int p = 0; p < 4; p++) {
        int r = rr + p * 4, c = cc;
        if (c < 32) {
          float t_ = 0.0f;
          #pragma unroll
          for (int k = 0; k < 32; k++)
            t_ += Ld[(32 + r) * 68 + k] * Wd[k * 68 + c];
          tsh[r * 33 + c] = t_;
        } else {
          int c2 = c - 32;
          float t_ = 0.0f;
          #pragma unroll
          for (int k = 0; k < 32; k++)
            t_ += Ld[(32 + r + 16) * 68 + k] * Wd[k * 68 + c2];
          tsh[(r + 16) * 33 + c2] = t_;
        }
      }
      __syncthreads();
      #pragma unroll
      for (int p = 0; p < 4; p++) {
        int r = rr + p * 4, c = cc;
        int r2 = (c < 32) ? r : r + 16;
        int c2 = (c < 32) ? c : c - 32;
        float x = 0.0f;
        #pragma unroll
        for (int k = 0; k < 32; k++)
          x -= Wd[(32 + r2) * 68 + 32 + k] * tsh[k * 33 + c2];
        Wd[(32 + r2) * 68 + c2] = x;
      }
    }
    __syncthreads();
    float* Wblk = W + (size_t)(jb * 64) * DD + jb * 64;
    for (int t = tid; t < 4096; t += 256) {
      int r = t >> 6, c = t & 63;
      float v = Wd[r * 68 + c];
      Wblk[(size_t)r * DD + c] = v;
      unsigned short h = f2bf(v), l = f2bf(v - bf2f(h));
      size_t prow = (size_t)(jb * 64 + r) * 1024 + jb * 64 + c;
      PW[prow] = h;
      PW[prow + 512] = l;
    }
  } else if (b == 8) {
    if (tid < 8) flags[tid] = 0;     // MUST re-zero: harness poisons ws between runs
    if (tid == 0) {
      float kap = fabsf(kappa[0]) + 1e-6f;
      float nu_ = fmaxf(nu[0], (float)(DD - 1) + 1e-6f);
      float common = nu_ + (float)SHOTS + 1.0f - (float)DD;
      float scale = (kap + SHOTS + 1.0f) / ((nu_ + SHOTS - DD + 1.0f) * (kap + SHOTS));
      cst[0] = kap;
      cst[1] = scale;
      cst[2] = common;
      cst[3] = 0.5f * (common + DD);
      cst[4] = lgammaf(0.5f * (common + DD)) - lgammaf(0.5f * common)
               - 0.5f * (float)DD * logf(common);
      cst[5] = -(kap + SHOTS);
      cst[6] = kap / (kap + SHOTS);
      cst[7] = 1.0f / (kap + SHOTS);
      cst[8] = (float)DD * logf(scale);
      cst[9] = -1.0f / (kap + SHOTS);
    }
  } else if (b < 73) {
    // mu/mun/rowmap with locally derived idx; also emit PX for mu rows
    int c = b - 9;
    if (tid < 64) {
      int lane = tid, cnt = 0;
      for (int i0 = 0; i0 < NSUP; i0 += 64) {
        int lab = labels[i0 + lane];
        unsigned long long mm = __ballot(lab == c);
        if (lab == c) {
          int pos = cnt + __popcll(mm & ((1ull << lane) - 1ull));
          if (pos < SHOTS) sidx[pos] = i0 + lane;
        }
        cnt += __popcll(mm);
      }
    }
    __syncthreads();
    if (tid < 17)
      rowmap[c * 17 + tid] = (tid < SHOTS) ? (QNQ + sidx[tid]) : (QNQ + NSUP + c);
    float kap = fabsf(kappa[0]) + 1e-6f;
    float cm = kap / (kap + SHOTS), cx = 1.0f / (kap + SHOTS);
    float* red = sh;
    float acc = 0.0f;
    size_t prow = (size_t)(3072 + c) * 1024;
    for (int d = tid; d < DD; d += 256) {
      float s = 0.0f;
      for (int sh_ = 0; sh_ < SHOTS; sh_++)
        s += Xs[(size_t)sidx[sh_] * DD + d];
      float v = cm * m[d] + cx * s;
      mu[(size_t)c * DD + d] = v;
      unsigned short h = f2bf(v), l = f2bf(v - bf2f(h));
      PX[prow + d] = h;
      PX[prow + 512 + d] = l;
      acc += v * v;
    }
    red[tid] = acc;
    __syncthreads();
    for (int off = 128; off > 0; off >>= 1) {
      if (tid < off) red[tid] += red[tid + off];
      __syncthreads();
    }
    if (tid == 0) mun[c] = red[0];
  } else {
    px_rows(Xq, Xs, PX, (b - 73) * 4);        // rows 0..1023
  }
}

// ---- 64x64 tile helpers (stride-68 LDS) ----
__device__ __forceinline__ void tile_stage(float* S, const float* __restrict__ G, int ldg) {
  int tid = threadIdx.x;
  #pragma unroll
  for (int p = 0; p < 4; p++) {
    int f4 = tid + 256 * p;
    int row = f4 >> 4, c4 = (f4 & 15) * 4;
    *(float4*)&S[row * 68 + c4] = *(const float4*)(G + (size_t)row * ldg + c4);
  }
}
__device__ __forceinline__ void tile_fma(float acc[4][4], const float* As, const float* Bs) {
  int tid = threadIdx.x, tr = tid >> 4, tc = tid & 15;
  #pragma unroll
  for (int kk = 0; kk < 64; kk++) {
    float a[4];
    #pragma unroll
    for (int x = 0; x < 4; x++) a[x] = As[(tr * 4 + x) * 68 + kk];
    float4 bv = *(const float4*)&Bs[kk * 68 + tc * 4];
    float bb[4] = {bv.x, bv.y, bv.z, bv.w};
    #pragma unroll
    for (int x = 0; x < 4; x++)
      #pragma unroll
      for (int y = 0; y < 4; y++) acc[x][y] += a[x] * bb[y];
  }
}
__device__ __forceinline__ void tile_out_neg(const float acc[4][4], float* W,
    unsigned short* PW, int gr0, int gc0) {
  int tid = threadIdx.x, tr = tid >> 4, tc = tid & 15;
  #pragma unroll
  for (int x = 0; x < 4; x++) {
    #pragma unroll
    for (int y = 0; y < 4; y++) {
      float v = -acc[x][y];
      W[(size_t)(gr0 + tr * 4 + x) * DD + gc0 + tc * 4 + y] = v;
      unsigned short h = f2bf(v), l = f2bf(v - bf2f(h));
      size_t prow = (size_t)(gr0 + tr * 4 + x) * 1024 + gc0 + tc * 4 + y;
      PW[prow] = h;
      PW[prow + 512] = l;
    }
  }
}

#define GBK 32
// ============ merged trinv level 128 + xmu partials + px rows 1024..2047 ============
__global__ __launch_bounds__(256) void k_m128_xmu(const float* __restrict__ tlow,
    const float* __restrict__ W_, float* __restrict__ Wout,
    const float* __restrict__ Xq, const float* __restrict__ Mu,
    float* __restrict__ xmup, unsigned short* __restrict__ PW,
    const float* __restrict__ Xs, unsigned short* __restrict__ PX) {
  __shared__ float sh[3 * 64 * 68];   // As | Bs | tsh = 52.2 KB
  int b = blockIdx.x, tid = threadIdx.x;
  if (b < 4) {
    float* As = sh;
    float* Bs = sh + 64 * 68;
    float* tsh = sh + 2 * 64 * 68;
    int base = b * 128;
    float tacc[4][4] = {};
    tile_stage(As, tlow + (size_t)(base + 64) * DD + base, DD);   // C
    tile_stage(Bs, W_ + (size_t)base * DD + base, DD);            // Ainv
    __syncthreads();
    tile_fma(tacc, As, Bs);
    __syncthreads();
    {
      int tr = tid >> 4, tc = tid & 15;
      #pragma unroll
      for (int x = 0; x < 4; x++)
        #pragma unroll
        for (int y = 0; y < 4; y++) tsh[(tr * 4 + x) * 68 + tc * 4 + y] = tacc[x][y];
    }
    tile_stage(As, W_ + (size_t)(base + 64) * DD + base + 64, DD); // Binv
    __syncthreads();
    float xacc[4][4] = {};
    tile_fma(xacc, As, tsh);
    tile_out_neg(xacc, Wout, PW, base + 64, base);
  } else if (b < 260) {     // xmu partials transposed: 32 q-cols x 64 c-rows
    float* Ms = sh;               // Mu: GBK k-rows x 64, stride 68
    float* Qs = sh + 64 * 68;     // Xq: GBK k-rows x 32, stride 36
    int xb = b - 4;
    int bm = (xb & 63) * 32, kq = xb >> 6;
    int tr = tid >> 4, tc = tid & 15;   // tr: c-group of 4, tc: q-pair
    float acc[4][2] = {};
    int k0s = kq * (DD / XKS), k0e = k0s + DD / XKS;
    for (int k0 = k0s; k0 < k0e; k0 += GBK) {
      #pragma unroll
      for (int p = 0; p < 2; p++) {
        int idx = tid + 256 * p;            // Mu 64x32 = 512 float4
        int row = idx >> 3, k4 = idx & 7;
        float4 v = *(const float4*)(Mu + (size_t)row * DD + k0 + k4 * 4);
        Ms[(k4 * 4 + 0) * 68 + row] = v.x; Ms[(k4 * 4 + 1) * 68 + row] = v.y;
        Ms[(k4 * 4 + 2) * 68 + row] = v.z; Ms[(k4 * 4 + 3) * 68 + row] = v.w;
      }
      {
        int row = tid >> 3, k4 = tid & 7;   // Xq 32x32 = 256 float4
        float4 v = *(const float4*)(Xq + (size_t)(bm + row) * DD + k0 + k4 * 4);
        Qs[(k4 * 4 + 0) * 36 + row] = v.x; Qs[(k4 * 4 + 1) * 36 + row] = v.y;
        Qs[(k4 * 4 + 2) * 36 + row] = v.z; Qs[(k4 * 4 + 3) * 36 + row] = v.w;
      }
      __syncthreads();
      #pragma unroll
      for (int kk = 0; kk < GBK; kk++) {
        float4 m0 = *(const float4*)&Ms[kk * 68 + tr * 4];
        float a[4] = {m0.x, m0.y, m0.z, m0.w};
        float q0 = Qs[kk * 36 + tc * 2], q1 = Qs[kk * 36 + tc * 2 + 1];
        #pragma unroll
        for (int y = 0; y < 4; y++) {
          acc[y][0] += a[y] * q0;
          acc[y][1] += a[y] * q1;
        }
      }
      __syncthreads();
    }
    #pragma unroll
    for (int y = 0; y < 4; y++) {
      float2 v = make_float2(acc[y][0], acc[y][1]);
      *(float2*)(xmup + ((size_t)kq * CNUM + tr * 4 + y) * QNQ + bm + tc * 2) = v;
    }
  } else {
    px_rows(Xq, Xs, PX, 1024 + (b - 260) * 4);   // rows 1024..2047
  }
}

// ============ merged trinv level 256 (+px rows 2048..3071) ============
__global__ __launch_bounds__(256) void k_m256(const float* __restrict__ tlow,
    float* __restrict__ W, unsigned short* __restrict__ PW,
    const float* __restrict__ Xq, const float* __restrict__ Xs,
    unsigned short* __restrict__ PX) {
  __shared__ float sh[3 * 64 * 68];
  int b = blockIdx.x, tid = threadIdx.x;
  if (b >= 8) { px_rows(Xq, Xs, PX, 2048 + (b - 8) * 4); return; }
  float* As = sh;
  float* Bs = sh + 64 * 68;
  float* tsh = sh + 2 * 64 * 68;
  int g = b >> 2, rem = b & 3, i = rem >> 1, j = rem & 1;
  int base = g * 256;
  float xacc[4][4] = {};
  for (int k = 0; k <= i; k++) {
    float tacc[4][4] = {};
    for (int l = j; l < 2; l++) {
      __syncthreads();
      tile_stage(As, tlow + (size_t)(base + 128 + 64 * k) * DD + base + 64 * l, DD); // C(k,l)
      tile_stage(Bs, W + (size_t)(base + 64 * l) * DD + base + 64 * j, DD);          // Ainv(l,j)
      __syncthreads();
      tile_fma(tacc, As, Bs);
    }
    __syncthreads();
    {
      int tr = tid >> 4, tc = tid & 15;
      #pragma unroll
      for (int x = 0; x < 4; x++)
        #pragma unroll
        for (int y = 0; y < 4; y++) tsh[(tr * 4 + x) * 68 + tc * 4 + y] = tacc[x][y];
    }
    tile_stage(As, W + (size_t)(base + 128 + 64 * i) * DD + base + 128 + 64 * k, DD); // Binv(i,k)
    __syncthreads();
    tile_fma(xacc, As, tsh);
  }
  tile_out_neg(xacc, W, PW, base + 128 + 64 * i, base + 64 * j);
}

// 64x64 NN GEMM tile on caller LDS (stride 68)
__device__ __forceinline__ void nn64_sh(float* As, float* Bs,
    const float* __restrict__ A, int lda, const float* __restrict__ B, int ldb,
    float* __restrict__ Cd, int ldc, int k0, int k1, float sgn,
    unsigned short* __restrict__ Pw, int gr0, int gc0) {
  int tid = threadIdx.x, tr = tid >> 4, tc = tid & 15;
  float acc[4][4] = {};
  for (int kc = k0; kc < k1; kc += 64) {
    #pragma unroll
    for (int p = 0; p < 4; p++) {
      int f4 = tid + 256 * p;
      int row = f4 >> 4, c4 = f4 & 15;
      *(float4*)&As[row * 68 + c4 * 4] = *(const float4*)(A + (size_t)row * lda + kc + c4 * 4);
      *(float4*)&Bs[row * 68 + c4 * 4] = *(const float4*)(B + (size_t)(kc + row) * ldb + c4 * 4);
    }
    __syncthreads();
    #pragma unroll
    for (int kk = 0; kk < 64; kk++) {
      float a[4];
      #pragma unroll
      for (int x = 0; x < 4; x++) a[x] = As[(tr * 4 + x) * 68 + kk];
      float4 bv = *(const float4*)&Bs[kk * 68 + tc * 4];
      float bb[4] = {bv.x, bv.y, bv.z, bv.w};
      #pragma unroll
      for (int x = 0; x < 4; x++)
        #pragma unroll
        for (int y = 0; y < 4; y++) acc[x][y] += a[x] * bb[y];
    }
    __syncthreads();
  }
  #pragma unroll
  for (int x = 0; x < 4; x++) {
    float4 v = make_float4(sgn * acc[x][0], sgn * acc[x][1],
                           sgn * acc[x][2], sgn * acc[x][3]);
    *(float4*)(Cd + (size_t)(tr * 4 + x) * ldc + tc * 4) = v;
    if (Pw) {
      size_t prow = (size_t)(gr0 + tr * 4 + x) * 1024 + gc0 + tc * 4;
      float vv[4] = {v.x, v.y, v.z, v.w};
      #pragma unroll
      for (int y = 0; y < 4; y++) {
        unsigned short h = f2bf(vv[y]), l = f2bf(vv[y] - bf2f(h));
        Pw[prow + y] = h;
        Pw[prow + 512 + y] = l;
      }
    }
  }
}

// ============ K_TRI_Y: triT + triX + ALL Y-tiles + wm, one launch ============
// Blocks:
//   [0,16)    triT            -> flags[0]
//   [16,212)  Y-tiles nt<4    (need W[<256] + PX: ready from prior launches)
//   [212,276) wm rows <256
//   [276,292) triX  [wait f0] -> flags[1]
//   [292,488) Y-tiles nt>=4 [wait f1]
//   [488,552) wm rows >=256 [wait f1]
// Safety: 2-deep chain; 276 dependency-free blocks busy from t=0; grid 552 <=
// 1024-block residency (256 thr, <=112 VGPR, 36.9 KB LDS -> 4 blocks/CU).
__global__ __launch_bounds__(256, 4) void k_tri_y(const float* __restrict__ tlow,
    float* __restrict__ W, float* __restrict__ T,
    const unsigned short* __restrict__ PX, unsigned short* __restrict__ PW,
    const float* __restrict__ m, float* __restrict__ Y,
    unsigned short* __restrict__ Pm, float* __restrict__ wm, int* flags) {
  __shared__ unsigned short ush[4 * 64 * PSTR];   // 36.9 KB (nn64 needs 34.8 KB)
  int b = blockIdx.x;
  if (b < 16) {
    int ti = b >> 2, tj = b & 3;
    const float* A = tlow + (size_t)(256 + ti * 64) * DD;
    const float* B = W + (size_t)tj * 64;
    float* Cd = T + (size_t)(ti * 64) * 256 + tj * 64;
    nn64_sh((float*)ush, (float*)ush + 64 * 68, A, DD, B, DD, Cd, 256,
            tj * 64, 256, 1.0f, nullptr, 0, 0);
    flag_signal(flags + 0);
  } else if (b < 212) {     // 196 Y-tiles, nt<4
    int t = b - 16;
    y_tile(PX, PW, Y, Pm, ush, t >> 2, t & 3);
  } else if (b < 276) {     // wm rows 0..255
    wm_rows(W, m, wm, (b - 212) * 4);
  } else if (b < 292) {     // triX
    flag_wait(flags + 0, 16);
    int rb = b - 276, ti = rb >> 2, tj = rb & 3;
    const float* A = W + (size_t)(256 + ti * 64) * DD + 256;
    const float* B = T + tj * 64;
    int gr0 = 256 + ti * 64, gc0 = tj * 64;
    float* Cd = W + (size_t)gr0 * DD + gc0;
    nn64_sh((float*)ush, (float*)ush + 64 * 68, A, DD, B, 256, Cd, DD,
            0, (ti + 1) * 64, -1.0f, PW, gr0, gc0);
    flag_signal(flags + 1);
  } else if (b < 488) {     // 196 Y-tiles, nt>=4 (need full W/PW)
    flag_wait(flags + 1, 16);
    int t = b - 292;
    y_tile(PX, PW, Y, Pm, ush, t >> 2, 4 + (t & 3));
  } else {                  // wm rows 256..511
    flag_wait(flags + 1, 16);
    wm_rows(W, m, wm, 256 + (b - 488) * 4);
  }
}

// ============ F5: gram-first + Rg 4-buf 8-iter 3-combo + query rows (8/block) ============
// grid 865 <= 1024 residency (4 blocks/CU at 36.9 KB LDS): no straggler wave.
__global__ __launch_bounds__(256) void f_z_rg_gram(const unsigned short* __restrict__ Pm,
    const float* __restrict__ Y, const float* __restrict__ tdiag,
    const int* __restrict__ rowmap, const float* __restrict__ Xq,
    const float* __restrict__ wm, float* __restrict__ cst,
    float* __restrict__ Rg,
    float* __restrict__ z, float* __restrict__ qn, float* __restrict__ yn,
    float* __restrict__ zg, float* __restrict__ Vmu, float* __restrict__ muBmu,
    float* __restrict__ Minv, float* __restrict__ bias) {
  __shared__ float sh[9216];   // 36.9 KB: 4x64xPSTR bf16 staging | gram arrays (9095 f)
  __shared__ float csmS;
  int b = blockIdx.x, tid = threadIdx.x;
  if (b < 64) {               // gram + register-GJ inverse + bias, one class per block
    int c = b;
    int lane = tid & 63, wave = tid >> 6;
    float* Ys  = sh;                 // 17 x 516
    float* aug = sh + 8772;          // 17 x 18 (left half only; identity in regs)
    float* zsv = aug + 306;          // 17
    float kap = cst[0], cst9 = cst[9];
    for (int t = tid; t < 17 * 128; t += 256) {
      int r = t >> 7, col = t & 127;
      *(float4*)&Ys[r * 516 + col * 4] =
          *(const float4*)(Y + (size_t)rowmap[c * 17 + r] * DD + col * 4);
    }
    float ldb_r = 0.0f;
    if (wave == 0) {
      float aa = 0.0f, ll = 0.0f;
      for (int t = lane; t < DD; t += 64) {
        float w = wm[t]; aa += w * w;
        ll += logf(fabsf(tdiag[t]));
      }
      #pragma unroll
      for (int off = 32; off > 0; off >>= 1) {
        aa += __shfl_xor(aa, off);
        ll += __shfl_xor(ll, off);
      }
      ldb_r = 2.0f * ll + logf(1.0f + kap * aa);
      if (lane == 0) csmS = kap / (1.0f + kap * aa);
    }
    __syncthreads();          // Ys + csmS ready
    if (wave > 0) {
      for (int a = wave - 1; a < 17; a += 3) {
        float s = 0.0f;
        for (int j = lane; j < 128; j += 64) {
          float4 yv = *(const float4*)&Ys[a * 516 + j * 4];
          float4 wv = *(const float4*)(wm + j * 4);
          s += yv.x * wv.x + yv.y * wv.y + yv.z * wv.z + yv.w * wv.w;
        }
        #pragma unroll
        for (int off = 32; off > 0; off >>= 1) s += __shfl_xor(s, off);
        if (lane == 0) zsv[a] = s;
      }
    }
    __syncthreads();          // zs ready
    float csm = csmS;
    for (int e = tid; e < 153; e += 256) {
      int a = (int)((sqrtf(8.0f * (float)e + 1.0f) - 1.0f) * 0.5f);
      while (((a + 1) * (a + 2)) / 2 <= e) a++;
      while ((a * (a + 1)) / 2 > e) a--;
      int bb = e - (a * (a + 1)) / 2;   // bb <= a
      const float* ra = &Ys[a * 516];
      const float* rb = &Ys[bb * 516];
      float s = 0.0f;
      for (int k = 0; k < 128; k++) {
        float4 va = *(const float4*)&ra[k * 4];
        float4 vb = *(const float4*)&rb[k * 4];
        s += va.x * vb.x + va.y * vb.y + va.z * vb.z + va.w * vb.w;
      }
      float g = s - csm * zsv[a] * zsv[bb];
      if (a == bb) g += (a < 16) ? 1.0f : cst9;
      aug[a * 18 + bb] = g;
      if (a != bb) aug[bb * 18 + a] = g;
    }
    __syncthreads();          // aug ready (LDS copy stays pristine below)
    if (wave == 0) {
      float colv[17];
      bool left = lane < 17;
      bool right = (lane >= 17 && lane < 34);
      #pragma unroll
      for (int r = 0; r < 17; r++) {
        float lv = aug[r * 18 + (lane & 31)];
        colv[r] = left ? lv : ((right && (lane - 17) == r) ? 1.0f : 0.0f);
      }
      float det = 0.0f;
      #pragma unroll
      for (int k = 0; k < 17; k++) {
        float best = fabsf(colv[k]); int bp = k;
        #pragma unroll
        for (int r = k + 1; r < 17; r++) {
          float v = fabsf(colv[r]);
          if (v > best) { best = v; bp = r; }
        }
        int p = __shfl(bp, k);
        float pv = colv[k];
        #pragma unroll
        for (int r = k + 1; r < 17; r++) pv = (p == r) ? colv[r] : pv;
        float oldk = colv[k];
        #pragma unroll
        for (int r = k + 1; r < 17; r++) colv[r] = (p == r) ? oldk : colv[r];
        colv[k] = pv;
        float piv = __shfl(pv, k);
        if (lane == 0) det += logf(fabsf(piv));
        float invp = 1.0f / piv;
        float rk = pv * invp;
        colv[k] = rk;
        #pragma unroll
        for (int r = 0; r < 17; r++) {
          if (r == k) continue;
          float ck = __shfl(colv[r], k);
          colv[r] = fmaf(-ck, rk, colv[r]);
        }
      }
      if (right) {
        int bb = lane - 17;
        #pragma unroll
        for (int r = 0; r < 17; r++)
          Minv[(size_t)c * 289 + r * 17 + bb] = colv[r];
      }
      if (lane == 0) {
        float slog = logf(fabsf(cst[5])) + det;
        float logdetSigma = cst[8] + ldb_r + slog;
        bias[c] = cst[4] - 0.5f * logdetSigma;
      }
    } else if (wave == 1) {   // concurrent with wave 0's GJ
      if (lane < 17) {
        float gv = aug[lane * 18 + 16];
        if (lane == 16) gv -= cst9;
        Vmu[c * 17 + lane] = gv;
        if (lane == 16) muBmu[c] = gv;
        zg[c * 17 + lane] = zsv[lane];
      }
    }
  } else if (b == 64) {       // SM consts for k_logits (identical arithmetic)
    if (tid < 64) {
      float aa = 0.0f, ll = 0.0f;
      for (int t = tid; t < DD; t += 64) {
        float w = wm[t]; aa += w * w;
        ll += logf(fabsf(tdiag[t]));
      }
      #pragma unroll
      for (int off = 32; off > 0; off >>= 1) {
        aa += __shfl_xor(aa, off);
        ll += __shfl_xor(ll, off);
      }
      if (tid == 0) {
        float kap = cst[0];
        cst[10] = kap / (1.0f + kap * aa);
        cst[11] = 2.0f * ll + logf(1.0f + kap * aa);
      }
    }
  } else if (b < 609) {       // Rg: 17x32 64x64 tiles; 4-buf 8-iter, lo*lo dropped
    unsigned short* ush = (unsigned short*)sh;
    unsigned short* AH = ush;
    unsigned short* AL = ush + 64 * PSTR;
    unsigned short* BH = ush + 2 * 64 * PSTR;
    unsigned short* BL = ush + 3 * 64 * PSTR;
    int rb = b - 65;
    int bm = (rb >> 5) * 64, bn = (rb & 31) * 64;
    int lane = tid & 63, wave = tid >> 6;
    int wr = wave >> 1, wc = wave & 1;
    int mrow = lane & 15, q = lane >> 4;
    int srowA[2];
    #pragma unroll
    for (int p = 0; p < 2; p++) srowA[p] = rowmap[bm + ((tid + 256 * p) >> 3)];
    f32x4 acc00 = {}, acc01 = {}, acc10 = {}, acc11 = {};
    for (int it = 0; it < 8; it++) {
      int kc = it * 64;
      #pragma unroll
      for (int p = 0; p < 2; p++) {
        int idx = tid + 256 * p;
        int row = idx >> 3, c8 = (idx & 7) * 8;
        *(short8*)&AH[row * PSTR + c8] =
            *(const short8*)(Pm + (size_t)srowA[p] * 1024 + kc + c8);
        *(short8*)&AL[row * PSTR + c8] =
            *(const short8*)(Pm + (size_t)srowA[p] * 1024 + 512 + kc + c8);
        *(short8*)&BH[row * PSTR + c8] =
            *(const short8*)(Pm + (size_t)(bn + row) * 1024 + kc + c8);
        *(short8*)&BL[row * PSTR + c8] =
            *(const short8*)(Pm + (size_t)(bn + row) * 1024 + 512 + kc + c8);
      }
      __syncthreads();
      #pragma unroll
      for (int ks = 0; ks < 2; ks++) {
        int ko = ks * 32 + q * 8;
        short8 ah0 = *(const short8*)&AH[(wr * 32 + mrow) * PSTR + ko];
        short8 ah1 = *(const short8*)&AH[(wr * 32 + 16 + mrow) * PSTR + ko];
        short8 al0 = *(const short8*)&AL[(wr * 32 + mrow) * PSTR + ko];
        short8 al1 = *(const short8*)&AL[(wr * 32 + 16 + mrow) * PSTR + ko];
        short8 bh0 = *(const short8*)&BH[(wc * 32 + mrow) * PSTR + ko];
        short8 bh1 = *(const short8*)&BH[(wc * 32 + 16 + mrow) * PSTR + ko];
        short8 bl0 = *(const short8*)&BL[(wc * 32 + mrow) * PSTR + ko];
        short8 bl1 = *(const short8*)&BL[(wc * 32 + 16 + mrow) * PSTR + ko];
        acc00 = __builtin_amdgcn_mfma_f32_16x16x32_bf16(ah0, bh0, acc00, 0, 0, 0);
        acc00 = __builtin_amdgcn_mfma_f32_16x16x32_bf16(ah0, bl0, acc00, 0, 0, 0);
        acc00 = __builtin_amdgcn_mfma_f32_16x16x32_bf16(al0, bh0, acc00, 0, 0, 0);
        acc01 = __builtin_amdgcn_mfma_f32_16x16x32_bf16(ah0, bh1, acc01, 0, 0, 0);
        acc01 = __builtin_amdgcn_mfma_f32_16x16x32_bf16(ah0, bl1, acc01, 0, 0, 0);
        acc01 = __builtin_amdgcn_mfma_f32_16x16x32_bf16(al0, bh1, acc01, 0, 0, 0);
        acc10 = __builtin_amdgcn_mfma_f32_16x16x32_bf16(ah1, bh0, acc10, 0, 0, 0);
        acc10 = __builtin_amdgcn_mfma_f32_16x16x32_bf16(ah1, bl0, acc10, 0, 0, 0);
        acc10 = __builtin_amdgcn_mfma_f32_16x16x32_bf16(al1, bh0, acc10, 0, 0, 0);
        acc11 = __builtin_amdgcn_mfma_f32_16x16x32_bf16(ah1, bh1, acc11, 0, 0, 0);
        acc11 = __builtin_amdgcn_mfma_f32_16x16x32_bf16(ah1, bl1, acc11, 0, 0, 0);
        acc11 = __builtin_amdgcn_mfma_f32_16x16x32_bf16(al1, bh1, acc11, 0, 0, 0);
      }
      __syncthreads();
    }
    #pragma unroll
    for (int r = 0; r < 4; r++) {
      int row0 = bm + wr * 32 + q * 4 + r;
      int row1 = row0 + 16;
      int col0 = bn + wc * 32 + mrow;
      Rg[(size_t)row0 * QNQ + col0]      = acc00[r];
      Rg[(size_t)row0 * QNQ + col0 + 16] = acc01[r];
      Rg[(size_t)row1 * QNQ + col0]      = acc10[r];
      Rg[(size_t)row1 * QNQ + col0 + 16] = acc11[r];
    }
  } else {                    // query rows (8 per block): z = Y.wm, qn, yn
    int wave = tid >> 6, lane = tid & 63;
    int base = (b - 609) * 8;
    #pragma unroll
    for (int rr = 0; rr < 2; rr++) {
      int row = base + rr * 4 + wave;
      const float* xr = Xq + (size_t)row * DD;
      const float* yr = Y + (size_t)row * DD;
      float sz = 0.0f, s1 = 0.0f, s2 = 0.0f;
      for (int j4 = lane; j4 < 128; j4 += 64) {
        float4 xv = *(const float4*)(xr + j4 * 4);
        float4 yv = *(const float4*)(yr + j4 * 4);
        float4 wv = *(const float4*)(wm + j4 * 4);
        sz += yv.x * wv.x + yv.y * wv.y + yv.z * wv.z + yv.w * wv.w;
        s1 += xv.x * xv.x + xv.y * xv.y + xv.z * xv.z + xv.w * xv.w;
        s2 += yv.x * yv.x + yv.y * yv.y + yv.z * yv.z + yv.w * yv.w;
      }
      for (int off = 32; off > 0; off >>= 1) {
        sz += __shfl_down(sz, off);
        s1 += __shfl_down(s1, off);
        s2 += __shfl_down(s2, off);
      }
      if (lane == 0) {
        z[row] = sz;
        qn[row] = s1;
        yn[row] = s2;
      }
    }
  }
}

// final epilogue: Woodbury-corrected Mahalanobis -> logits[q,c]
__global__ __launch_bounds__(256) void k_logits(const float* __restrict__ Rg,
    const float* z, const float* zg,
    const float* Vmu, const float* muBmu, const float* mun, const float* yn,
    const float* qn, const float* xmup, const float* Minv, const float* bias,
    const float* cst, float* out) {
  __shared__ float Ms[289], Vs[17], Zs[17];
  int c = blockIdx.y;
  int q = blockIdx.x * 256 + threadIdx.x;
  for (int t = threadIdx.x; t < 289; t += 256) Ms[t] = Minv[(size_t)c * 289 + t];
  if (threadIdx.x < 17) {
    Vs[threadIdx.x] = Vmu[c * 17 + threadIdx.x];
    Zs[threadIdx.x] = zg[c * 17 + threadIdx.x];
  }
  __syncthreads();
  float csm = cst[10], scale = cst[1], common = cst[2], coef = cst[3];
  float zq = z[q];
  float r[17];
  float xBmu = 0.0f;
  for (int a = 0; a < 17; a++) {
    float raw = Rg[(size_t)(c * 17 + a) * QNQ + q] - csm * Zs[a] * zq;
    if (a == 16) xBmu = raw;
    r[a] = raw - Vs[a];
  }
  float qB = yn[q] - csm * zq * zq;
  float quadB = qB - 2.0f * xBmu + muBmu[c];
  float corr = 0.0f;
  for (int a = 0; a < 17; a++) {
    float e = 0.0f;
    for (int bb = 0; bb < 17; bb++) e += Ms[a * 17 + bb] * r[bb];
    corr += r[a] * e;
  }
  float distB = (quadB - corr) / scale;
  float xm = 0.0f;
  #pragma unroll
  for (int p = 0; p < XKS; p++)
    xm += xmup[((size_t)(p * CNUM + c)) * QNQ + q];   // [p][c][q]: coalesced in q
  float dn = qn[q] - 2.0f * xm + mun[c];
  float dist = (1.0f - REGP) * distB + REGP * dn;
  out[(size_t)q * CNUM + c] = bias[c] - coef * log1pf(dist / common);
}

// ---------------- host ----------------
extern "C" void kernel_launch(void* const* d_in, const int* in_sizes, int n_in,
                              void* d_out, int out_size, void* d_ws, size_t ws_size,
                              hipStream_t stream) {
  const float* Xs    = (const float*)d_in[0];
  const int*   labels= (const int*)d_in[1];
  const float* Xq    = (const float*)d_in[2];
  const float* m     = (const float*)d_in[3];
  const float* kappa = (const float*)d_in[4];
  const float* nu    = (const float*)d_in[5];
  const float* tdiag = (const float*)d_in[6];
  const float* tlow  = (const float*)d_in[7];
  float* ws = (float*)d_ws;
  float* W    = ws + OFF_W;
  float* mu   = ws + OFF_MU;
  float* Y    = ws + OFF_Y;
  float* z    = ws + OFF_Z;
  float* wm   = ws + OFF_WM;
  float* cst  = ws + OFF_CONST;
  int*   rmap = (int*)(ws + OFF_RMAP);
  float* zg   = ws + OFF_ZG;
  float* Vmu  = ws + OFF_VMU;
  float* muBmu= ws + OFF_MUBMU;
  float* mun  = ws + OFF_MUN;
  float* Minv = ws + OFF_MINV;
  float* bias = ws + OFF_BIAS;
  float* qn   = ws + OFF_QNRM;
  float* yn   = ws + OFF_YN;
  float* xmup = ws + OFF_XMU;
  float* Rg   = ws + OFF_RG;
  unsigned short* P  = (unsigned short*)(ws + OFF_P);
  unsigned short* PX = (unsigned short*)(ws + OFF_PX);
  unsigned short* PW = (unsigned short*)(ws + OFF_PW);
  int*   flags = (int*)(ws + OFF_FLAGS);
  float* Ttmp = ws + OFF_RG;       // trinv scratch, reused (Rg written later)
  float* out  = (float*)d_out;

  // F1: diag-inv(+PW) + consts+flags + mu/mun/rowmap(+PX) + px rows 0..1023
  f_init<<<73 + 256, 256, 0, stream>>>(tdiag, tlow, kappa, nu, labels, Xs, Xq, m,
                                       W, cst, rmap, mu, mun, PX, PW, flags);
  // m128 trinv + xmu + px rows 1024..2047
  k_m128_xmu<<<260 + 256, 256, 0, stream>>>(tlow, W, W, Xq, mu, xmup, PW, Xs, PX);
  // m256 trinv + px rows 2048..3071 (PX complete after this launch)
  k_m256<<<8 + 256, 256, 0, stream>>>(tlow, W, PW, Xq, Xs, PX);
  // merged: triT -> triX (flag) -> Y-late/wm-late (flag), Y-early/wm-early free
  k_tri_y<<<552, 256, 0, stream>>>(tlow, W, Ttmp, PX, PW, m, Y, P, wm, flags);
  // gram-first + Rg 4-buf 8-iter 3-combo + query rows (8/block): grid 865
  f_z_rg_gram<<<64 + 1 + 544 + 256, 256, 0, stream>>>(P, Y, tdiag, rmap, Xq, wm,
                                                      cst, Rg, z, qn, yn,
                                                      zg, Vmu, muBmu, Minv, bias);
  k_logits<<<dim3(QNQ / 256, CNUM), 256, 0, stream>>>(Rg, z, zg, Vmu, muBmu,
                                                      mun, yn, qn, xmup, Minv, bias,
                                                      cst, out);
  (void)in_sizes; (void)n_in; (void)out_size; (void)ws_size;
}

// Round 9
// 186.650 us; speedup vs baseline: 1.0529x; 1.0529x over previous
//
#include <hip/hip_runtime.h>
#include <math.h>

// Problem dims (fixed by setup_inputs)
#define DD    512
#define CNUM  64
#define SHOTS 16
#define NSUP  1024
#define QNQ   2048
#define REGP  0.1f
#define XKS   4      // xmu split-K parts

typedef __attribute__((ext_vector_type(8))) short short8;   // 8 bf16 = 4 VGPRs
typedef __attribute__((ext_vector_type(4))) float f32x4;

// bf16 round-to-nearest-even, raw bits
__device__ __forceinline__ unsigned short f2bf(float f) {
  unsigned int u = __float_as_uint(f);
  unsigned int r = (u + 0x7fffu + ((u >> 16) & 1u)) >> 16;
  return (unsigned short)r;
}
__device__ __forceinline__ float bf2f(unsigned short h) {
  return __uint_as_float((unsigned int)h << 16);
}

// ---------------- workspace layout (in floats) ----------------
static constexpr size_t OFF_W     = 0;                       // 512*512
static constexpr size_t OFF_MU    = OFF_W     + 512*512;     // 64*512
static constexpr size_t OFF_Y     = OFF_MU    + 64*512;      // 3136*512
static constexpr size_t OFF_Z     = OFF_Y     + 3136*512;    // 2048
static constexpr size_t OFF_WM    = OFF_Z     + 3136;        // 512
static constexpr size_t OFF_CONST = OFF_WM    + 512;         // 16
static constexpr size_t OFF_RMAP  = OFF_CONST + 16;          // 1088 ints
static constexpr size_t OFF_ZG    = OFF_RMAP  + 1088;        // 1088
static constexpr size_t OFF_VMU   = OFF_ZG    + 1088;        // 1088
static constexpr size_t OFF_MUBMU = OFF_VMU   + 1088;        // 64
static constexpr size_t OFF_MUN   = OFF_MUBMU + 64;          // 64
static constexpr size_t OFF_MINV  = OFF_MUN   + 64;          // 64*289
static constexpr size_t OFF_BIAS  = OFF_MINV  + 64*289;      // 64
static constexpr size_t OFF_QNRM  = OFF_BIAS  + 64;          // 2048
static constexpr size_t OFF_YN    = OFF_QNRM  + 2048;        // 2048
static constexpr size_t OFF_XMU   = OFF_YN    + 2048;        // XKS*64*2048 ([p][c][q])
static constexpr size_t OFF_RG    = OFF_XMU   + (size_t)XKS*2048*64; // 1088*2048 (also trinv T)
static constexpr size_t OFF_P     = OFF_RG    + 1088*2048;   // 3136*1024 bf16 (Y split)
static constexpr size_t OFF_PX    = OFF_P     + 3136*512;    // 3136*1024 bf16 (X split)
static constexpr size_t OFF_PW    = OFF_PX    + 3136*512;    // 512*1024 bf16 (W split)

// consts: 0 kap, 1 scale, 2 common, 3 coef, 4 bias0, 5 jlast,
// 6 cmu_m, 7 cmu_x, 8 D*log(scale), 9 Jinv_last, 10 c_sm, 11 logdetB

// ---- PX staging for 4 global rows (Xq then Xs), one block of 256 ----
__device__ __forceinline__ void px_rows(const float* __restrict__ Xq,
    const float* __restrict__ Xs, unsigned short* __restrict__ PX, int r0) {
  int tid = threadIdx.x;
  int row = r0 + (tid >> 6), lane = tid & 63;
  const float* src = (row < QNQ) ? Xq + (size_t)row * DD
                                 : Xs + (size_t)(row - QNQ) * DD;
  size_t prow = (size_t)row * 1024;
  #pragma unroll
  for (int p = 0; p < 2; p++) {
    int col = lane * 8 + p * 4;
    float4 v = *(const float4*)(src + col);
    ushort4 hi, lo;
    hi.x = f2bf(v.x); lo.x = f2bf(v.x - bf2f(hi.x));
    hi.y = f2bf(v.y); lo.y = f2bf(v.y - bf2f(hi.y));
    hi.z = f2bf(v.z); lo.z = f2bf(v.z - bf2f(hi.z));
    hi.w = f2bf(v.w); lo.w = f2bf(v.w - bf2f(hi.w));
    *(ushort4*)(PX + prow + col) = hi;
    *(ushort4*)(PX + prow + 512 + col) = lo;
  }
}

#define PSTR 72   // LDS row stride in bf16 (144 B: 2-way banks = free)

// ---- shared Y-tile body (3-combo bf16-split MFMA, tri-skip) ----
__device__ __forceinline__ void y_tile(const unsigned short* __restrict__ PX,
    const unsigned short* __restrict__ PW, float* __restrict__ Y,
    unsigned short* __restrict__ Pm, unsigned short* ush, int mt, int nt) {
  unsigned short* AshH = ush;
  unsigned short* AshL = ush + 64 * PSTR;
  unsigned short* BshH = ush + 2 * 64 * PSTR;
  unsigned short* BshL = ush + 3 * 64 * PSTR;
  int tid = threadIdx.x;
  int bm = mt * 64, bn = nt * 64;
  int lane = tid & 63, wave = tid >> 6;
  int wr = wave >> 1, wc = wave & 1;
  int mrow = lane & 15, q = lane >> 4;
  f32x4 acc00 = {}, acc01 = {}, acc10 = {}, acc11 = {};
  int kchunks = nt + 1;   // W lower-triangular: k < bn+64
  for (int it = 0; it < kchunks; it++) {
    int kc = it * 64;
    #pragma unroll
    for (int p = 0; p < 2; p++) {
      int idx = tid + 256 * p;
      int row = idx >> 3, c8 = (idx & 7) * 8;
      *(short8*)&AshH[row * PSTR + c8] =
          *(const short8*)(PX + (size_t)(bm + row) * 1024 + kc + c8);
      *(short8*)&AshL[row * PSTR + c8] =
          *(const short8*)(PX + (size_t)(bm + row) * 1024 + 512 + kc + c8);
      *(short8*)&BshH[row * PSTR + c8] =
          *(const short8*)(PW + (size_t)(bn + row) * 1024 + kc + c8);
      *(short8*)&BshL[row * PSTR + c8] =
          *(const short8*)(PW + (size_t)(bn + row) * 1024 + 512 + kc + c8);
    }
    __syncthreads();
    #pragma unroll
    for (int ks = 0; ks < 2; ks++) {
      int ko = ks * 32 + q * 8;
      short8 ah0 = *(const short8*)&AshH[(wr * 32 + mrow) * PSTR + ko];
      short8 ah1 = *(const short8*)&AshH[(wr * 32 + 16 + mrow) * PSTR + ko];
      short8 al0 = *(const short8*)&AshL[(wr * 32 + mrow) * PSTR + ko];
      short8 al1 = *(const short8*)&AshL[(wr * 32 + 16 + mrow) * PSTR + ko];
      short8 bh0 = *(const short8*)&BshH[(wc * 32 + mrow) * PSTR + ko];
      short8 bh1 = *(const short8*)&BshH[(wc * 32 + 16 + mrow) * PSTR + ko];
      short8 bl0 = *(const short8*)&BshL[(wc * 32 + mrow) * PSTR + ko];
      short8 bl1 = *(const short8*)&BshL[(wc * 32 + 16 + mrow) * PSTR + ko];
      acc00 = __builtin_amdgcn_mfma_f32_16x16x32_bf16(ah0, bh0, acc00, 0, 0, 0);
      acc00 = __builtin_amdgcn_mfma_f32_16x16x32_bf16(ah0, bl0, acc00, 0, 0, 0);
      acc00 = __builtin_amdgcn_mfma_f32_16x16x32_bf16(al0, bh0, acc00, 0, 0, 0);
      acc01 = __builtin_amdgcn_mfma_f32_16x16x32_bf16(ah0, bh1, acc01, 0, 0, 0);
      acc01 = __builtin_amdgcn_mfma_f32_16x16x32_bf16(ah0, bl1, acc01, 0, 0, 0);
      acc01 = __builtin_amdgcn_mfma_f32_16x16x32_bf16(al0, bh1, acc01, 0, 0, 0);
      acc10 = __builtin_amdgcn_mfma_f32_16x16x32_bf16(ah1, bh0, acc10, 0, 0, 0);
      acc10 = __builtin_amdgcn_mfma_f32_16x16x32_bf16(ah1, bl0, acc10, 0, 0, 0);
      acc10 = __builtin_amdgcn_mfma_f32_16x16x32_bf16(al1, bh0, acc10, 0, 0, 0);
      acc11 = __builtin_amdgcn_mfma_f32_16x16x32_bf16(ah1, bh1, acc11, 0, 0, 0);
      acc11 = __builtin_amdgcn_mfma_f32_16x16x32_bf16(ah1, bl1, acc11, 0, 0, 0);
      acc11 = __builtin_amdgcn_mfma_f32_16x16x32_bf16(al1, bh1, acc11, 0, 0, 0);
    }
    __syncthreads();
  }
  #pragma unroll
  for (int r = 0; r < 4; r++) {
    int row0 = bm + wr * 32 + q * 4 + r;
    int row1 = row0 + 16;
    int col0 = bn + wc * 32 + mrow;
    float vv[4] = {acc00[r], acc01[r], acc10[r], acc11[r]};
    int rows[4] = {row0, row0, row1, row1};
    int cols[4] = {col0, col0 + 16, col0, col0 + 16};
    #pragma unroll
    for (int e = 0; e < 4; e++) {
      Y[(size_t)rows[e] * DD + cols[e]] = vv[e];
      unsigned short h = f2bf(vv[e]), l = f2bf(vv[e] - bf2f(h));
      Pm[(size_t)rows[e] * 1024 + cols[e]] = h;
      Pm[(size_t)rows[e] * 1024 + 512 + cols[e]] = l;
    }
  }
}

// ---- wm rows: wm[row] = W[row, 0..row] . m (4 rows per block) ----
__device__ __forceinline__ void wm_rows(const float* __restrict__ W,
    const float* __restrict__ m, float* __restrict__ wm, int r0) {
  int tid = threadIdx.x;
  int wave = tid >> 6, lane = tid & 63;
  int row = r0 + wave;
  float s = 0.0f;
  for (int j = lane; j <= row; j += 64) s += W[(size_t)row * DD + j] * m[j];
  for (int off = 32; off > 0; off >>= 1) s += __shfl_down(s, off);
  if (lane == 0) wm[row] = s;
}

// ============ F1: diag-inv(+PW), consts, mu/mun/rowmap(+PX), px rows 0..1023 ============
__global__ __launch_bounds__(256) void f_init(const float* tdiag, const float* tlow,
    const float* kappa, const float* nu, const int* labels, const float* Xs,
    const float* Xq, const float* m, float* W, float* cst,
    int* rowmap, float* mu, float* mun,
    unsigned short* PX, unsigned short* PW) {
  __shared__ float sh[2 * 64 * 68 + 32 * 33];   // Ld | Wd | tsh = 39 KB
  __shared__ int sidx[SHOTS];
  int b = blockIdx.x, tid = threadIdx.x;
  if (b < 8) {
    // diag 64x64 inverse via blocked 16->32->64 (critical path: dispatch first)
    int jb = b;
    float* Ld = sh;                   // [64][68]
    float* Wd = sh + 64 * 68;         // [64][68]
    float* tsh = sh + 2 * 64 * 68;    // [32][33]
    for (int t = tid; t < 4096; t += 256) {
      int r = t >> 6, c = t & 63;
      int gr = jb * 64 + r;
      float v = (r == c) ? fabsf(tdiag[gr])
              : (r > c ? tlow[(size_t)gr * DD + jb * 64 + c] : 0.0f);
      Ld[r * 68 + c] = v;
      Wd[r * 68 + c] = 0.0f;
    }
    __syncthreads();
    if (tid < 64) {
      // 16x16 base inverse, column t of sub-block s — register chain
      int s = tid >> 4, t = tid & 15;
      int r0 = s * 16;
      float wreg[16];
      #pragma unroll
      for (int i = 0; i < 16; i++) {
        float w = (i == t) ? 1.0f : 0.0f;
        #pragma unroll
        for (int k = 0; k < 16; k++)
          if (k < i) w -= Ld[(r0 + i) * 68 + r0 + k] * wreg[k];
        wreg[i] = w / Ld[(r0 + i) * 68 + r0 + i];
      }
      #pragma unroll
      for (int i = 0; i < 16; i++) Wd[(r0 + i) * 68 + r0 + t] = wreg[i];
    }
    __syncthreads();
    for (int g2 = 0; g2 < 2; g2++) {
      int r0 = g2 * 32 + 16, c0 = g2 * 32;
      int rr = tid >> 4, cc = tid & 15;
      float t_ = 0.0f;
      #pragma unroll
      for (int k = 0; k < 16; k++)
        t_ += Ld[(r0 + rr) * 68 + c0 + k] * Wd[(c0 + k) * 68 + c0 + cc];
      tsh[rr * 33 + cc] = t_;
      __syncthreads();
      float x = 0.0f;
      #pragma unroll
      for (int k = 0; k < 16; k++)
        x -= Wd[(r0 + rr) * 68 + r0 + k] * tsh[k * 33 + cc];
      Wd[(r0 + rr) * 68 + c0 + cc] = x;
      __syncthreads();
    }
    {
      int rr = tid >> 6, cc = tid & 63;
      #pragma unroll
      for (int p = 0; p < 4; p++) {
        int r = rr + p * 4, c = cc;
        if (c < 32) {
          float t_ = 0.0f;
          #pragma unroll
          for (int k = 0; k < 32; k++)
            t_ += Ld[(32 + r) * 68 + k] * Wd[k * 68 + c];
          tsh[r * 33 + c] = t_;
        } else {
          int c2 = c - 32;
          float t_ = 0.0f;
          #pragma unroll
          for (int k = 0; k < 32; k++)
            t_ += Ld[(32 + r + 16) * 68 + k] * Wd[k * 68 + c2];
          tsh[(r + 16) * 33 + c2] = t_;
        }
      }
      __syncthreads();
      #pragma unroll
      for (int p = 0; p < 4; p++) {
        int r = rr + p * 4, c = cc;
        int r2 = (c < 32) ? r : r + 16;
        int c2 = (c < 32) ? c : c - 32;
        float x = 0.0f;
        #pragma unroll
        for (int k = 0; k < 32; k++)
          x -= Wd[(32 + r2) * 68 + 32 + k] * tsh[k * 33 + c2];
        Wd[(32 + r2) * 68 + c2] = x;
      }
    }
    __syncthreads();
    float* Wblk = W + (size_t)(jb * 64) * DD + jb * 64;
    for (int t = tid; t < 4096; t += 256) {
      int r = t >> 6, c = t & 63;
      float v = Wd[r * 68 + c];
      Wblk[(size_t)r * DD + c] = v;
      unsigned short h = f2bf(v), l = f2bf(v - bf2f(h));
      size_t prow = (size_t)(jb * 64 + r) * 1024 + jb * 64 + c;
      PW[prow] = h;
      PW[prow + 512] = l;
    }
  } else if (b == 8) {
    if (tid == 0) {
      float kap = fabsf(kappa[0]) + 1e-6f;
      float nu_ = fmaxf(nu[0], (float)(DD - 1) + 1e-6f);
      float common = nu_ + (float)SHOTS + 1.0f - (float)DD;
      float scale = (kap + SHOTS + 1.0f) / ((nu_ + SHOTS - DD + 1.0f) * (kap + SHOTS));
      cst[0] = kap;
      cst[1] = scale;
      cst[2] = common;
      cst[3] = 0.5f * (common + DD);
      cst[4] = lgammaf(0.5f * (common + DD)) - lgammaf(0.5f * common)
               - 0.5f * (float)DD * logf(common);
      cst[5] = -(kap + SHOTS);
      cst[6] = kap / (kap + SHOTS);
      cst[7] = 1.0f / (kap + SHOTS);
      cst[8] = (float)DD * logf(scale);
      cst[9] = -1.0f / (kap + SHOTS);
    }
  } else if (b < 73) {
    // mu/mun/rowmap with locally derived idx; also emit PX for mu rows
    int c = b - 9;
    if (tid < 64) {
      int lane = tid, cnt = 0;
      for (int i0 = 0; i0 < NSUP; i0 += 64) {
        int lab = labels[i0 + lane];
        unsigned long long mm = __ballot(lab == c);
        if (lab == c) {
          int pos = cnt + __popcll(mm & ((1ull << lane) - 1ull));
          if (pos < SHOTS) sidx[pos] = i0 + lane;
        }
        cnt += __popcll(mm);
      }
    }
    __syncthreads();
    if (tid < 17)
      rowmap[c * 17 + tid] = (tid < SHOTS) ? (QNQ + sidx[tid]) : (QNQ + NSUP + c);
    float kap = fabsf(kappa[0]) + 1e-6f;
    float cm = kap / (kap + SHOTS), cx = 1.0f / (kap + SHOTS);
    float* red = sh;
    float acc = 0.0f;
    size_t prow = (size_t)(3072 + c) * 1024;
    for (int d = tid; d < DD; d += 256) {
      float s = 0.0f;
      for (int sh_ = 0; sh_ < SHOTS; sh_++)
        s += Xs[(size_t)sidx[sh_] * DD + d];
      float v = cm * m[d] + cx * s;
      mu[(size_t)c * DD + d] = v;
      unsigned short h = f2bf(v), l = f2bf(v - bf2f(h));
      PX[prow + d] = h;
      PX[prow + 512 + d] = l;
      acc += v * v;
    }
    red[tid] = acc;
    __syncthreads();
    for (int off = 128; off > 0; off >>= 1) {
      if (tid < off) red[tid] += red[tid + off];
      __syncthreads();
    }
    if (tid == 0) mun[c] = red[0];
  } else {
    px_rows(Xq, Xs, PX, (b - 73) * 4);        // rows 0..1023
  }
}

// ---- 64x64 tile helpers (stride-68 LDS) ----
__device__ __forceinline__ void tile_stage(float* S, const float* __restrict__ G, int ldg) {
  int tid = threadIdx.x;
  #pragma unroll
  for (int p = 0; p < 4; p++) {
    int f4 = tid + 256 * p;
    int row = f4 >> 4, c4 = (f4 & 15) * 4;
    *(float4*)&S[row * 68 + c4] = *(const float4*)(G + (size_t)row * ldg + c4);
  }
}
__device__ __forceinline__ void tile_fma(float acc[4][4], const float* As, const float* Bs) {
  int tid = threadIdx.x, tr = tid >> 4, tc = tid & 15;
  #pragma unroll
  for (int kk = 0; kk < 64; kk++) {
    float a[4];
    #pragma unroll
    for (int x = 0; x < 4; x++) a[x] = As[(tr * 4 + x) * 68 + kk];
    float4 bv = *(const float4*)&Bs[kk * 68 + tc * 4];
    float bb[4] = {bv.x, bv.y, bv.z, bv.w};
    #pragma unroll
    for (int x = 0; x < 4; x++)
      #pragma unroll
      for (int y = 0; y < 4; y++) acc[x][y] += a[x] * bb[y];
  }
}
__device__ __forceinline__ void tile_out_neg(const float acc[4][4], float* W,
    unsigned short* PW, int gr0, int gc0) {
  int tid = threadIdx.x, tr = tid >> 4, tc = tid & 15;
  #pragma unroll
  for (int x = 0; x < 4; x++) {
    #pragma unroll
    for (int y = 0; y < 4; y++) {
      float v = -acc[x][y];
      W[(size_t)(gr0 + tr * 4 + x) * DD + gc0 + tc * 4 + y] = v;
      unsigned short h = f2bf(v), l = f2bf(v - bf2f(h));
      size_t prow = (size_t)(gr0 + tr * 4 + x) * 1024 + gc0 + tc * 4 + y;
      PW[prow] = h;
      PW[prow + 512] = l;
    }
  }
}

#define GBK 32
// ============ merged trinv level 128 + xmu partials + px rows 1024..2047 ============
__global__ __launch_bounds__(256) void k_m128_xmu(const float* __restrict__ tlow,
    const float* __restrict__ W_, float* __restrict__ Wout,
    const float* __restrict__ Xq, const float* __restrict__ Mu,
    float* __restrict__ xmup, unsigned short* __restrict__ PW,
    const float* __restrict__ Xs, unsigned short* __restrict__ PX) {
  __shared__ float sh[3 * 64 * 68];   // As | Bs | tsh = 52.2 KB
  int b = blockIdx.x, tid = threadIdx.x;
  if (b < 4) {
    float* As = sh;
    float* Bs = sh + 64 * 68;
    float* tsh = sh + 2 * 64 * 68;
    int base = b * 128;
    float tacc[4][4] = {};
    tile_stage(As, tlow + (size_t)(base + 64) * DD + base, DD);   // C
    tile_stage(Bs, W_ + (size_t)base * DD + base, DD);            // Ainv
    __syncthreads();
    tile_fma(tacc, As, Bs);
    __syncthreads();
    {
      int tr = tid >> 4, tc = tid & 15;
      #pragma unroll
      for (int x = 0; x < 4; x++)
        #pragma unroll
        for (int y = 0; y < 4; y++) tsh[(tr * 4 + x) * 68 + tc * 4 + y] = tacc[x][y];
    }
    tile_stage(As, W_ + (size_t)(base + 64) * DD + base + 64, DD); // Binv
    __syncthreads();
    float xacc[4][4] = {};
    tile_fma(xacc, As, tsh);
    tile_out_neg(xacc, Wout, PW, base + 64, base);
  } else if (b < 260) {     // xmu partials transposed: 32 q-cols x 64 c-rows
    float* Ms = sh;               // Mu: GBK k-rows x 64, stride 68
    float* Qs = sh + 64 * 68;     // Xq: GBK k-rows x 32, stride 36
    int xb = b - 4;
    int bm = (xb & 63) * 32, kq = xb >> 6;
    int tr = tid >> 4, tc = tid & 15;   // tr: c-group of 4, tc: q-pair
    float acc[4][2] = {};
    int k0s = kq * (DD / XKS), k0e = k0s + DD / XKS;
    for (int k0 = k0s; k0 < k0e; k0 += GBK) {
      #pragma unroll
      for (int p = 0; p < 2; p++) {
        int idx = tid + 256 * p;            // Mu 64x32 = 512 float4
        int row = idx >> 3, k4 = idx & 7;
        float4 v = *(const float4*)(Mu + (size_t)row * DD + k0 + k4 * 4);
        Ms[(k4 * 4 + 0) * 68 + row] = v.x; Ms[(k4 * 4 + 1) * 68 + row] = v.y;
        Ms[(k4 * 4 + 2) * 68 + row] = v.z; Ms[(k4 * 4 + 3) * 68 + row] = v.w;
      }
      {
        int row = tid >> 3, k4 = tid & 7;   // Xq 32x32 = 256 float4
        float4 v = *(const float4*)(Xq + (size_t)(bm + row) * DD + k0 + k4 * 4);
        Qs[(k4 * 4 + 0) * 36 + row] = v.x; Qs[(k4 * 4 + 1) * 36 + row] = v.y;
        Qs[(k4 * 4 + 2) * 36 + row] = v.z; Qs[(k4 * 4 + 3) * 36 + row] = v.w;
      }
      __syncthreads();
      #pragma unroll
      for (int kk = 0; kk < GBK; kk++) {
        float4 m0 = *(const float4*)&Ms[kk * 68 + tr * 4];
        float a[4] = {m0.x, m0.y, m0.z, m0.w};
        float q0 = Qs[kk * 36 + tc * 2], q1 = Qs[kk * 36 + tc * 2 + 1];
        #pragma unroll
        for (int y = 0; y < 4; y++) {
          acc[y][0] += a[y] * q0;
          acc[y][1] += a[y] * q1;
        }
      }
      __syncthreads();
    }
    #pragma unroll
    for (int y = 0; y < 4; y++) {
      float2 v = make_float2(acc[y][0], acc[y][1]);
      *(float2*)(xmup + ((size_t)kq * CNUM + tr * 4 + y) * QNQ + bm + tc * 2) = v;
    }
  } else {
    px_rows(Xq, Xs, PX, 1024 + (b - 260) * 4);   // rows 1024..2047
  }
}

// ============ merged trinv level 256 (+px rows 2048..3071) ============
__global__ __launch_bounds__(256) void k_m256(const float* __restrict__ tlow,
    float* __restrict__ W, unsigned short* __restrict__ PW,
    const float* __restrict__ Xq, const float* __restrict__ Xs,
    unsigned short* __restrict__ PX) {
  __shared__ float sh[3 * 64 * 68];
  int b = blockIdx.x, tid = threadIdx.x;
  if (b >= 8) { px_rows(Xq, Xs, PX, 2048 + (b - 8) * 4); return; }
  float* As = sh;
  float* Bs = sh + 64 * 68;
  float* tsh = sh + 2 * 64 * 68;
  int g = b >> 2, rem = b & 3, i = rem >> 1, j = rem & 1;
  int base = g * 256;
  float xacc[4][4] = {};
  for (int k = 0; k <= i; k++) {
    float tacc[4][4] = {};
    for (int l = j; l < 2; l++) {
      __syncthreads();
      tile_stage(As, tlow + (size_t)(base + 128 + 64 * k) * DD + base + 64 * l, DD); // C(k,l)
      tile_stage(Bs, W + (size_t)(base + 64 * l) * DD + base + 64 * j, DD);          // Ainv(l,j)
      __syncthreads();
      tile_fma(tacc, As, Bs);
    }
    __syncthreads();
    {
      int tr = tid >> 4, tc = tid & 15;
      #pragma unroll
      for (int x = 0; x < 4; x++)
        #pragma unroll
        for (int y = 0; y < 4; y++) tsh[(tr * 4 + x) * 68 + tc * 4 + y] = tacc[x][y];
    }
    tile_stage(As, W + (size_t)(base + 128 + 64 * i) * DD + base + 128 + 64 * k, DD); // Binv(i,k)
    __syncthreads();
    tile_fma(xacc, As, tsh);
  }
  tile_out_neg(xacc, W, PW, base + 128 + 64 * i, base + 64 * j);
}

// 64x64 NN GEMM tile on caller LDS (stride 68)
__device__ __forceinline__ void nn64_sh(float* As, float* Bs,
    const float* __restrict__ A, int lda, const float* __restrict__ B, int ldb,
    float* __restrict__ Cd, int ldc, int k0, int k1, float sgn,
    unsigned short* __restrict__ Pw, int gr0, int gc0) {
  int tid = threadIdx.x, tr = tid >> 4, tc = tid & 15;
  float acc[4][4] = {};
  for (int kc = k0; kc < k1; kc += 64) {
    #pragma unroll
    for (int p = 0; p < 4; p++) {
      int f4 = tid + 256 * p;
      int row = f4 >> 4, c4 = f4 & 15;
      *(float4*)&As[row * 68 + c4 * 4] = *(const float4*)(A + (size_t)row * lda + kc + c4 * 4);
      *(float4*)&Bs[row * 68 + c4 * 4] = *(const float4*)(B + (size_t)(kc + row) * ldb + c4 * 4);
    }
    __syncthreads();
    #pragma unroll
    for (int kk = 0; kk < 64; kk++) {
      float a[4];
      #pragma unroll
      for (int x = 0; x < 4; x++) a[x] = As[(tr * 4 + x) * 68 + kk];
      float4 bv = *(const float4*)&Bs[kk * 68 + tc * 4];
      float bb[4] = {bv.x, bv.y, bv.z, bv.w};
      #pragma unroll
      for (int x = 0; x < 4; x++)
        #pragma unroll
        for (int y = 0; y < 4; y++) acc[x][y] += a[x] * bb[y];
    }
    __syncthreads();
  }
  #pragma unroll
  for (int x = 0; x < 4; x++) {
    float4 v = make_float4(sgn * acc[x][0], sgn * acc[x][1],
                           sgn * acc[x][2], sgn * acc[x][3]);
    *(float4*)(Cd + (size_t)(tr * 4 + x) * ldc + tc * 4) = v;
    if (Pw) {
      size_t prow = (size_t)(gr0 + tr * 4 + x) * 1024 + gc0 + tc * 4;
      float vv[4] = {v.x, v.y, v.z, v.w};
      #pragma unroll
      for (int y = 0; y < 4; y++) {
        unsigned short h = f2bf(vv[y]), l = f2bf(vv[y] - bf2f(h));
        Pw[prow + y] = h;
        Pw[prow + 512 + y] = l;
      }
    }
  }
}

// ============ trinv level-512 T + Y-tiles nt<4 + wm rows<256 ============
__global__ __launch_bounds__(256) void k_triT(const float* __restrict__ tlow,
    const float* __restrict__ W, float* __restrict__ T,
    const unsigned short* __restrict__ PX, const unsigned short* __restrict__ PW,
    const float* __restrict__ m, float* __restrict__ Y,
    unsigned short* __restrict__ Pm, float* __restrict__ wm) {
  __shared__ unsigned short ush[4 * 64 * PSTR];   // 36.9 KB (fits nn64's 34.8 KB too)
  int b = blockIdx.x;
  if (b < 16) {
    int ti = b >> 2, tj = b & 3;
    const float* A = tlow + (size_t)(256 + ti * 64) * DD;
    const float* B = W + (size_t)tj * 64;
    float* Cd = T + (size_t)(ti * 64) * 256 + tj * 64;
    nn64_sh((float*)ush, (float*)ush + 64 * 68, A, DD, B, DD, Cd, 256,
            tj * 64, 256, 1.0f, nullptr, 0, 0);
  } else if (b < 212) {     // 196 Y-tiles, nt<4
    int t = b - 16;
    y_tile(PX, PW, Y, Pm, ush, t >> 2, t & 3);
  } else {                  // wm rows 0..255
    wm_rows(W, m, wm, (b - 212) * 4);
  }
}

// ============ trinv level-512 X (emits PW) ============
__global__ __launch_bounds__(256) void k_triX(float* __restrict__ W,
                                              const float* __restrict__ T,
                                              unsigned short* __restrict__ PW) {
  __shared__ float sh[2 * 64 * 68];
  int b = blockIdx.x;
  int ti = b >> 2, tj = b & 3;
  const float* A = W + (size_t)(256 + ti * 64) * DD + 256;
  const float* B = T + tj * 64;
  int gr0 = 256 + ti * 64, gc0 = tj * 64;
  float* Cd = W + (size_t)gr0 * DD + gc0;
  nn64_sh(sh, sh + 64 * 68, A, DD, B, 256, Cd, DD, 0, (ti + 1) * 64, -1.0f, PW, gr0, gc0);
}

// ============ F3: remaining Y-tiles (nt>=4, need full W) + wm rows>=256 ============
__global__ __launch_bounds__(256) void f_y_wm(const unsigned short* __restrict__ PX,
    const unsigned short* __restrict__ PW, const float* __restrict__ W,
    const float* __restrict__ m, float* __restrict__ Y,
    unsigned short* __restrict__ Pm, float* __restrict__ wm) {
  __shared__ unsigned short ush[4 * 64 * PSTR];
  int b = blockIdx.x;
  if (b < 196) {
    y_tile(PX, PW, Y, Pm, ush, b >> 2, 4 + (b & 3));
  } else {                  // wm rows 256..511
    wm_rows(W, m, wm, 256 + (b - 196) * 4);
  }
}

// ============ F5: gram-first + Rg 4-buf 8-iter 3-combo (XCD-swizzled) + query rows ============
// grid 865 <= 1024 residency (4 blocks/CU at 36.9 KB LDS): no straggler wave.
__global__ __launch_bounds__(256) void f_z_rg_gram(const unsigned short* __restrict__ Pm,
    const float* __restrict__ Y, const float* __restrict__ tdiag,
    const int* __restrict__ rowmap, const float* __restrict__ Xq,
    const float* __restrict__ wm, float* __restrict__ cst,
    float* __restrict__ Rg,
    float* __restrict__ z, float* __restrict__ qn, float* __restrict__ yn,
    float* __restrict__ zg, float* __restrict__ Vmu, float* __restrict__ muBmu,
    float* __restrict__ Minv, float* __restrict__ bias) {
  __shared__ float sh[9216];   // 36.9 KB: 4x64xPSTR bf16 staging | gram arrays (9095 f)
  __shared__ float csmS;
  int b = blockIdx.x, tid = threadIdx.x;
  if (b < 64) {               // gram + register-GJ inverse + bias, one class per block
    int c = b;
    int lane = tid & 63, wave = tid >> 6;
    float* Ys  = sh;                 // 17 x 516
    float* aug = sh + 8772;          // 17 x 18 (left half only; identity in regs)
    float* zsv = aug + 306;          // 17
    float kap = cst[0], cst9 = cst[9];
    for (int t = tid; t < 17 * 128; t += 256) {
      int r = t >> 7, col = t & 127;
      *(float4*)&Ys[r * 516 + col * 4] =
          *(const float4*)(Y + (size_t)rowmap[c * 17 + r] * DD + col * 4);
    }
    float ldb_r = 0.0f;
    if (wave == 0) {
      float aa = 0.0f, ll = 0.0f;
      for (int t = lane; t < DD; t += 64) {
        float w = wm[t]; aa += w * w;
        ll += logf(fabsf(tdiag[t]));
      }
      #pragma unroll
      for (int off = 32; off > 0; off >>= 1) {
        aa += __shfl_xor(aa, off);
        ll += __shfl_xor(ll, off);
      }
      ldb_r = 2.0f * ll + logf(1.0f + kap * aa);
      if (lane == 0) csmS = kap / (1.0f + kap * aa);
    }
    __syncthreads();          // Ys + csmS ready
    if (wave > 0) {
      for (int a = wave - 1; a < 17; a += 3) {
        float s = 0.0f;
        for (int j = lane; j < 128; j += 64) {
          float4 yv = *(const float4*)&Ys[a * 516 + j * 4];
          float4 wv = *(const float4*)(wm + j * 4);
          s += yv.x * wv.x + yv.y * wv.y + yv.z * wv.z + yv.w * wv.w;
        }
        #pragma unroll
        for (int off = 32; off > 0; off >>= 1) s += __shfl_xor(s, off);
        if (lane == 0) zsv[a] = s;
      }
    }
    __syncthreads();          // zs ready
    float csm = csmS;
    for (int e = tid; e < 153; e += 256) {
      int a = (int)((sqrtf(8.0f * (float)e + 1.0f) - 1.0f) * 0.5f);
      while (((a + 1) * (a + 2)) / 2 <= e) a++;
      while ((a * (a + 1)) / 2 > e) a--;
      int bb = e - (a * (a + 1)) / 2;   // bb <= a
      const float* ra = &Ys[a * 516];
      const float* rb = &Ys[bb * 516];
      float s = 0.0f;
      for (int k = 0; k < 128; k++) {
        float4 va = *(const float4*)&ra[k * 4];
        float4 vb = *(const float4*)&rb[k * 4];
        s += va.x * vb.x + va.y * vb.y + va.z * vb.z + va.w * vb.w;
      }
      float g = s - csm * zsv[a] * zsv[bb];
      if (a == bb) g += (a < 16) ? 1.0f : cst9;
      aug[a * 18 + bb] = g;
      if (a != bb) aug[bb * 18 + a] = g;
    }
    __syncthreads();          // aug ready (LDS copy stays pristine below)
    if (wave == 0) {
      float colv[17];
      bool left = lane < 17;
      bool right = (lane >= 17 && lane < 34);
      #pragma unroll
      for (int r = 0; r < 17; r++) {
        float lv = aug[r * 18 + (lane & 31)];
        colv[r] = left ? lv : ((right && (lane - 17) == r) ? 1.0f : 0.0f);
      }
      float det = 0.0f;
      #pragma unroll
      for (int k = 0; k < 17; k++) {
        float best = fabsf(colv[k]); int bp = k;
        #pragma unroll
        for (int r = k + 1; r < 17; r++) {
          float v = fabsf(colv[r]);
          if (v > best) { best = v; bp = r; }
        }
        int p = __shfl(bp, k);
        float pv = colv[k];
        #pragma unroll
        for (int r = k + 1; r < 17; r++) pv = (p == r) ? colv[r] : pv;
        float oldk = colv[k];
        #pragma unroll
        for (int r = k + 1; r < 17; r++) colv[r] = (p == r) ? oldk : colv[r];
        colv[k] = pv;
        float piv = __shfl(pv, k);
        if (lane == 0) det += logf(fabsf(piv));
        float invp = 1.0f / piv;
        float rk = pv * invp;
        colv[k] = rk;
        #pragma unroll
        for (int r = 0; r < 17; r++) {
          if (r == k) continue;
          float ck = __shfl(colv[r], k);
          colv[r] = fmaf(-ck, rk, colv[r]);
        }
      }
      if (right) {
        int bb = lane - 17;
        #pragma unroll
        for (int r = 0; r < 17; r++)
          Minv[(size_t)c * 289 + r * 17 + bb] = colv[r];
      }
      if (lane == 0) {
        float slog = logf(fabsf(cst[5])) + det;
        float logdetSigma = cst[8] + ldb_r + slog;
        bias[c] = cst[4] - 0.5f * logdetSigma;
      }
    } else if (wave == 1) {   // concurrent with wave 0's GJ
      if (lane < 17) {
        float gv = aug[lane * 18 + 16];
        if (lane == 16) gv -= cst9;
        Vmu[c * 17 + lane] = gv;
        if (lane == 16) muBmu[c] = gv;
        zg[c * 17 + lane] = zsv[lane];
      }
    }
  } else if (b == 64) {       // SM consts for k_logits (identical arithmetic)
    if (tid < 64) {
      float aa = 0.0f, ll = 0.0f;
      for (int t = tid; t < DD; t += 64) {
        float w = wm[t]; aa += w * w;
        ll += logf(fabsf(tdiag[t]));
      }
      #pragma unroll
      for (int off = 32; off > 0; off >>= 1) {
        aa += __shfl_xor(aa, off);
        ll += __shfl_xor(ll, off);
      }
      if (tid == 0) {
        float kap = cst[0];
        cst[10] = kap / (1.0f + kap * aa);
        cst[11] = 2.0f * ll + logf(1.0f + kap * aa);
      }
    }
  } else if (b < 609) {       // Rg: 17x32 64x64 tiles; 4-buf 8-iter, lo*lo dropped
    // XCD-aware swizzle (T1): 544 = 8*68 exactly; each XCD gets a contiguous
    // 68-tile chunk (~2 bm-groups) so the gathered A-panel stays in its L2.
    unsigned short* ush = (unsigned short*)sh;
    unsigned short* AH = ush;
    unsigned short* AL = ush + 64 * PSTR;
    unsigned short* BH = ush + 2 * 64 * PSTR;
    unsigned short* BL = ush + 3 * 64 * PSTR;
    int rb = b - 65;
    rb = (rb & 7) * 68 + (rb >> 3);   // bijective: [0,544) -> [0,544)
    int bm = (rb >> 5) * 64, bn = (rb & 31) * 64;
    int lane = tid & 63, wave = tid >> 6;
    int wr = wave >> 1, wc = wave & 1;
    int mrow = lane & 15, q = lane >> 4;
    int srowA[2];
    #pragma unroll
    for (int p = 0; p < 2; p++) srowA[p] = rowmap[bm + ((tid + 256 * p) >> 3)];
    f32x4 acc00 = {}, acc01 = {}, acc10 = {}, acc11 = {};
    for (int it = 0; it < 8; it++) {
      int kc = it * 64;
      #pragma unroll
      for (int p = 0; p < 2; p++) {
        int idx = tid + 256 * p;
        int row = idx >> 3, c8 = (idx & 7) * 8;
        *(short8*)&AH[row * PSTR + c8] =
            *(const short8*)(Pm + (size_t)srowA[p] * 1024 + kc + c8);
        *(short8*)&AL[row * PSTR + c8] =
            *(const short8*)(Pm + (size_t)srowA[p] * 1024 + 512 + kc + c8);
        *(short8*)&BH[row * PSTR + c8] =
            *(const short8*)(Pm + (size_t)(bn + row) * 1024 + kc + c8);
        *(short8*)&BL[row * PSTR + c8] =
            *(const short8*)(Pm + (size_t)(bn + row) * 1024 + 512 + kc + c8);
      }
      __syncthreads();
      #pragma unroll
      for (int ks = 0; ks < 2; ks++) {
        int ko = ks * 32 + q * 8;
        short8 ah0 = *(const short8*)&AH[(wr * 32 + mrow) * PSTR + ko];
        short8 ah1 = *(const short8*)&AH[(wr * 32 + 16 + mrow) * PSTR + ko];
        short8 al0 = *(const short8*)&AL[(wr * 32 + mrow) * PSTR + ko];
        short8 al1 = *(const short8*)&AL[(wr * 32 + 16 + mrow) * PSTR + ko];
        short8 bh0 = *(const short8*)&BH[(wc * 32 + mrow) * PSTR + ko];
        short8 bh1 = *(const short8*)&BH[(wc * 32 + 16 + mrow) * PSTR + ko];
        short8 bl0 = *(const short8*)&BL[(wc * 32 + mrow) * PSTR + ko];
        short8 bl1 = *(const short8*)&BL[(wc * 32 + 16 + mrow) * PSTR + ko];
        acc00 = __builtin_amdgcn_mfma_f32_16x16x32_bf16(ah0, bh0, acc00, 0, 0, 0);
        acc00 = __builtin_amdgcn_mfma_f32_16x16x32_bf16(ah0, bl0, acc00, 0, 0, 0);
        acc00 = __builtin_amdgcn_mfma_f32_16x16x32_bf16(al0, bh0, acc00, 0, 0, 0);
        acc01 = __builtin_amdgcn_mfma_f32_16x16x32_bf16(ah0, bh1, acc01, 0, 0, 0);
        acc01 = __builtin_amdgcn_mfma_f32_16x16x32_bf16(ah0, bl1, acc01, 0, 0, 0);
        acc01 = __builtin_amdgcn_mfma_f32_16x16x32_bf16(al0, bh1, acc01, 0, 0, 0);
        acc10 = __builtin_amdgcn_mfma_f32_16x16x32_bf16(ah1, bh0, acc10, 0, 0, 0);
        acc10 = __builtin_amdgcn_mfma_f32_16x16x32_bf16(ah1, bl0, acc10, 0, 0, 0);
        acc10 = __builtin_amdgcn_mfma_f32_16x16x32_bf16(al1, bh0, acc10, 0, 0, 0);
        acc11 = __builtin_amdgcn_mfma_f32_16x16x32_bf16(ah1, bh1, acc11, 0, 0, 0);
        acc11 = __builtin_amdgcn_mfma_f32_16x16x32_bf16(ah1, bl1, acc11, 0, 0, 0);
        acc11 = __builtin_amdgcn_mfma_f32_16x16x32_bf16(al1, bh1, acc11, 0, 0, 0);
      }
      __syncthreads();
    }
    #pragma unroll
    for (int r = 0; r < 4; r++) {
      int row0 = bm + wr * 32 + q * 4 + r;
      int row1 = row0 + 16;
      int col0 = bn + wc * 32 + mrow;
      Rg[(size_t)row0 * QNQ + col0]      = acc00[r];
      Rg[(size_t)row0 * QNQ + col0 + 16] = acc01[r];
      Rg[(size_t)row1 * QNQ + col0]      = acc10[r];
      Rg[(size_t)row1 * QNQ + col0 + 16] = acc11[r];
    }
  } else {                    // query rows (8 per block): z = Y.wm, qn, yn
    int wave = tid >> 6, lane = tid & 63;
    int base = (b - 609) * 8;
    #pragma unroll
    for (int rr = 0; rr < 2; rr++) {
      int row = base + rr * 4 + wave;
      const float* xr = Xq + (size_t)row * DD;
      const float* yr = Y + (size_t)row * DD;
      float sz = 0.0f, s1 = 0.0f, s2 = 0.0f;
      for (int j4 = lane; j4 < 128; j4 += 64) {
        float4 xv = *(const float4*)(xr + j4 * 4);
        float4 yv = *(const float4*)(yr + j4 * 4);
        float4 wv = *(const float4*)(wm + j4 * 4);
        sz += yv.x * wv.x + yv.y * wv.y + yv.z * wv.z + yv.w * wv.w;
        s1 += xv.x * xv.x + xv.y * xv.y + xv.z * xv.z + xv.w * xv.w;
        s2 += yv.x * yv.x + yv.y * yv.y + yv.z * yv.z + yv.w * yv.w;
      }
      for (int off = 32; off > 0; off >>= 1) {
        sz += __shfl_down(sz, off);
        s1 += __shfl_down(s1, off);
        s2 += __shfl_down(s2, off);
      }
      if (lane == 0) {
        z[row] = sz;
        qn[row] = s1;
        yn[row] = s2;
      }
    }
  }
}

// final epilogue: Woodbury-corrected Mahalanobis -> logits[q,c]
__global__ __launch_bounds__(256) void k_logits(const float* __restrict__ Rg,
    const float* z, const float* zg,
    const float* Vmu, const float* muBmu, const float* mun, const float* yn,
    const float* qn, const float* xmup, const float* Minv, const float* bias,
    const float* cst, float* out) {
  __shared__ float Ms[289], Vs[17], Zs[17];
  int c = blockIdx.y;
  int q = blockIdx.x * 256 + threadIdx.x;
  for (int t = threadIdx.x; t < 289; t += 256) Ms[t] = Minv[(size_t)c * 289 + t];
  if (threadIdx.x < 17) {
    Vs[threadIdx.x] = Vmu[c * 17 + threadIdx.x];
    Zs[threadIdx.x] = zg[c * 17 + threadIdx.x];
  }
  __syncthreads();
  float csm = cst[10], scale = cst[1], common = cst[2], coef = cst[3];
  float zq = z[q];
  float r[17];
  float xBmu = 0.0f;
  for (int a = 0; a < 17; a++) {
    float raw = Rg[(size_t)(c * 17 + a) * QNQ + q] - csm * Zs[a] * zq;
    if (a == 16) xBmu = raw;
    r[a] = raw - Vs[a];
  }
  float qB = yn[q] - csm * zq * zq;
  float quadB = qB - 2.0f * xBmu + muBmu[c];
  float corr = 0.0f;
  for (int a = 0; a < 17; a++) {
    float e = 0.0f;
    for (int bb = 0; bb < 17; bb++) e += Ms[a * 17 + bb] * r[bb];
    corr += r[a] * e;
  }
  float distB = (quadB - corr) / scale;
  float xm = 0.0f;
  #pragma unroll
  for (int p = 0; p < XKS; p++)
    xm += xmup[((size_t)(p * CNUM + c)) * QNQ + q];   // [p][c][q]: coalesced in q
  float dn = qn[q] - 2.0f * xm + mun[c];
  float dist = (1.0f - REGP) * distB + REGP * dn;
  out[(size_t)q * CNUM + c] = bias[c] - coef * log1pf(dist / common);
}

// ---------------- host ----------------
extern "C" void kernel_launch(void* const* d_in, const int* in_sizes, int n_in,
                              void* d_out, int out_size, void* d_ws, size_t ws_size,
                              hipStream_t stream) {
  const float* Xs    = (const float*)d_in[0];
  const int*   labels= (const int*)d_in[1];
  const float* Xq    = (const float*)d_in[2];
  const float* m     = (const float*)d_in[3];
  const float* kappa = (const float*)d_in[4];
  const float* nu    = (const float*)d_in[5];
  const float* tdiag = (const float*)d_in[6];
  const float* tlow  = (const float*)d_in[7];
  float* ws = (float*)d_ws;
  float* W    = ws + OFF_W;
  float* mu   = ws + OFF_MU;
  float* Y    = ws + OFF_Y;
  float* z    = ws + OFF_Z;
  float* wm   = ws + OFF_WM;
  float* cst  = ws + OFF_CONST;
  int*   rmap = (int*)(ws + OFF_RMAP);
  float* zg   = ws + OFF_ZG;
  float* Vmu  = ws + OFF_VMU;
  float* muBmu= ws + OFF_MUBMU;
  float* mun  = ws + OFF_MUN;
  float* Minv = ws + OFF_MINV;
  float* bias = ws + OFF_BIAS;
  float* qn   = ws + OFF_QNRM;
  float* yn   = ws + OFF_YN;
  float* xmup = ws + OFF_XMU;
  float* Rg   = ws + OFF_RG;
  unsigned short* P  = (unsigned short*)(ws + OFF_P);
  unsigned short* PX = (unsigned short*)(ws + OFF_PX);
  unsigned short* PW = (unsigned short*)(ws + OFF_PW);
  float* Ttmp = ws + OFF_RG;       // trinv scratch, reused (Rg written later)
  float* out  = (float*)d_out;

  // F1: diag-inv(+PW) + consts + mu/mun/rowmap(+PX) + px rows 0..1023
  f_init<<<73 + 256, 256, 0, stream>>>(tdiag, tlow, kappa, nu, labels, Xs, Xq, m,
                                       W, cst, rmap, mu, mun, PX, PW);
  // m128 trinv + xmu + px rows 1024..2047
  k_m128_xmu<<<260 + 256, 256, 0, stream>>>(tlow, W, W, Xq, mu, xmup, PW, Xs, PX);
  // m256 trinv + px rows 2048..3071 (PX complete after this launch)
  k_m256<<<8 + 256, 256, 0, stream>>>(tlow, W, PW, Xq, Xs, PX);
  // triT + early Y-tiles (nt<4, only need W[<256]) + wm rows<256
  k_triT<<<16 + 196 + 64, 256, 0, stream>>>(tlow, W, Ttmp, PX, PW, m, Y, P, wm);
  // triX (completes W/PW)
  k_triX<<<16, 256, 0, stream>>>(W, Ttmp, PW);
  // late Y-tiles (nt>=4) + wm rows>=256
  f_y_wm<<<196 + 64, 256, 0, stream>>>(PX, PW, W, m, Y, P, wm);
  // gram-first + Rg (XCD-swizzled) + query rows (8/block): grid 865
  f_z_rg_gram<<<64 + 1 + 544 + 256, 256, 0, stream>>>(P, Y, tdiag, rmap, Xq, wm,
                                                      cst, Rg, z, qn, yn,
                                                      zg, Vmu, muBmu, Minv, bias);
  k_logits<<<dim3(QNQ / 256, CNUM), 256, 0, stream>>>(Rg, z, zg, Vmu, muBmu,
                                                      mun, yn, qn, xmup, Minv, bias,
                                                      cst, out);
  (void)in_sizes; (void)n_in; (void)out_size; (void)ws_size;
}

// Round 10
// 183.286 us; speedup vs baseline: 1.0722x; 1.0184x over previous
//
#include <hip/hip_runtime.h>
#include <math.h>

// Problem dims (fixed by setup_inputs)
#define DD    512
#define CNUM  64
#define SHOTS 16
#define NSUP  1024
#define QNQ   2048
#define REGP  0.1f
#define XKS   4      // xmu split-K parts

typedef __attribute__((ext_vector_type(8))) short short8;   // 8 bf16 = 4 VGPRs
typedef __attribute__((ext_vector_type(4))) float f32x4;

// bf16 round-to-nearest-even, raw bits
__device__ __forceinline__ unsigned short f2bf(float f) {
  unsigned int u = __float_as_uint(f);
  unsigned int r = (u + 0x7fffu + ((u >> 16) & 1u)) >> 16;
  return (unsigned short)r;
}
__device__ __forceinline__ float bf2f(unsigned short h) {
  return __uint_as_float((unsigned int)h << 16);
}

// ---------------- workspace layout (in floats) ----------------
static constexpr size_t OFF_W     = 0;                       // 512*512
static constexpr size_t OFF_MU    = OFF_W     + 512*512;     // 64*512
static constexpr size_t OFF_Y     = OFF_MU    + 64*512;      // 3136*512
static constexpr size_t OFF_Z     = OFF_Y     + 3136*512;    // 2048
static constexpr size_t OFF_WM    = OFF_Z     + 3136;        // 512
static constexpr size_t OFF_CONST = OFF_WM    + 512;         // 16
static constexpr size_t OFF_RMAP  = OFF_CONST + 16;          // 1088 ints
static constexpr size_t OFF_ZG    = OFF_RMAP  + 1088;        // 1088
static constexpr size_t OFF_VMU   = OFF_ZG    + 1088;        // 1088
static constexpr size_t OFF_MUBMU = OFF_VMU   + 1088;        // 64
static constexpr size_t OFF_MUN   = OFF_MUBMU + 64;          // 64
static constexpr size_t OFF_MINV  = OFF_MUN   + 64;          // 64*289
static constexpr size_t OFF_BIAS  = OFF_MINV  + 64*289;      // 64
static constexpr size_t OFF_QNRM  = OFF_BIAS  + 64;          // 2048
static constexpr size_t OFF_YN    = OFF_QNRM  + 2048;        // 2048
static constexpr size_t OFF_XMU   = OFF_YN    + 2048;        // XKS*64*2048 ([p][c][q])
static constexpr size_t OFF_RG    = OFF_XMU   + (size_t)XKS*2048*64; // 1088*2048 (also trinv T)
static constexpr size_t OFF_P     = OFF_RG    + 1088*2048;   // 3136*1024 bf16 (Y split)
static constexpr size_t OFF_PX    = OFF_P     + 3136*512;    // 3136*1024 bf16 (X split)
static constexpr size_t OFF_PW    = OFF_PX    + 3136*512;    // 512*1024 bf16 (W split)

// consts: 0 kap, 1 scale, 2 common, 3 coef, 4 bias0, 5 jlast,
// 6 cmu_m, 7 cmu_x, 8 D*log(scale), 9 Jinv_last, 10 c_sm, 11 logdetB

// ---- PX staging for 4 global rows (Xq then Xs), one block of 256 ----
__device__ __forceinline__ void px_rows(const float* __restrict__ Xq,
    const float* __restrict__ Xs, unsigned short* __restrict__ PX, int r0) {
  int tid = threadIdx.x;
  int row = r0 + (tid >> 6), lane = tid & 63;
  const float* src = (row < QNQ) ? Xq + (size_t)row * DD
                                 : Xs + (size_t)(row - QNQ) * DD;
  size_t prow = (size_t)row * 1024;
  #pragma unroll
  for (int p = 0; p < 2; p++) {
    int col = lane * 8 + p * 4;
    float4 v = *(const float4*)(src + col);
    ushort4 hi, lo;
    hi.x = f2bf(v.x); lo.x = f2bf(v.x - bf2f(hi.x));
    hi.y = f2bf(v.y); lo.y = f2bf(v.y - bf2f(hi.y));
    hi.z = f2bf(v.z); lo.z = f2bf(v.z - bf2f(hi.z));
    hi.w = f2bf(v.w); lo.w = f2bf(v.w - bf2f(hi.w));
    *(ushort4*)(PX + prow + col) = hi;
    *(ushort4*)(PX + prow + 512 + col) = lo;
  }
}

#define PSTR 72   // LDS row stride in bf16 (144 B: 2-way banks = free)

// ---- shared Y-tile body (3-combo bf16-split MFMA, tri-skip) ----
__device__ __forceinline__ void y_tile(const unsigned short* __restrict__ PX,
    const unsigned short* __restrict__ PW, float* __restrict__ Y,
    unsigned short* __restrict__ Pm, unsigned short* ush, int mt, int nt) {
  unsigned short* AshH = ush;
  unsigned short* AshL = ush + 64 * PSTR;
  unsigned short* BshH = ush + 2 * 64 * PSTR;
  unsigned short* BshL = ush + 3 * 64 * PSTR;
  int tid = threadIdx.x;
  int bm = mt * 64, bn = nt * 64;
  int lane = tid & 63, wave = tid >> 6;
  int wr = wave >> 1, wc = wave & 1;
  int mrow = lane & 15, q = lane >> 4;
  f32x4 acc00 = {}, acc01 = {}, acc10 = {}, acc11 = {};
  int kchunks = nt + 1;   // W lower-triangular: k < bn+64
  for (int it = 0; it < kchunks; it++) {
    int kc = it * 64;
    #pragma unroll
    for (int p = 0; p < 2; p++) {
      int idx = tid + 256 * p;
      int row = idx >> 3, c8 = (idx & 7) * 8;
      *(short8*)&AshH[row * PSTR + c8] =
          *(const short8*)(PX + (size_t)(bm + row) * 1024 + kc + c8);
      *(short8*)&AshL[row * PSTR + c8] =
          *(const short8*)(PX + (size_t)(bm + row) * 1024 + 512 + kc + c8);
      *(short8*)&BshH[row * PSTR + c8] =
          *(const short8*)(PW + (size_t)(bn + row) * 1024 + kc + c8);
      *(short8*)&BshL[row * PSTR + c8] =
          *(const short8*)(PW + (size_t)(bn + row) * 1024 + 512 + kc + c8);
    }
    __syncthreads();
    #pragma unroll
    for (int ks = 0; ks < 2; ks++) {
      int ko = ks * 32 + q * 8;
      short8 ah0 = *(const short8*)&AshH[(wr * 32 + mrow) * PSTR + ko];
      short8 ah1 = *(const short8*)&AshH[(wr * 32 + 16 + mrow) * PSTR + ko];
      short8 al0 = *(const short8*)&AshL[(wr * 32 + mrow) * PSTR + ko];
      short8 al1 = *(const short8*)&AshL[(wr * 32 + 16 + mrow) * PSTR + ko];
      short8 bh0 = *(const short8*)&BshH[(wc * 32 + mrow) * PSTR + ko];
      short8 bh1 = *(const short8*)&BshH[(wc * 32 + 16 + mrow) * PSTR + ko];
      short8 bl0 = *(const short8*)&BshL[(wc * 32 + mrow) * PSTR + ko];
      short8 bl1 = *(const short8*)&BshL[(wc * 32 + 16 + mrow) * PSTR + ko];
      acc00 = __builtin_amdgcn_mfma_f32_16x16x32_bf16(ah0, bh0, acc00, 0, 0, 0);
      acc00 = __builtin_amdgcn_mfma_f32_16x16x32_bf16(ah0, bl0, acc00, 0, 0, 0);
      acc00 = __builtin_amdgcn_mfma_f32_16x16x32_bf16(al0, bh0, acc00, 0, 0, 0);
      acc01 = __builtin_amdgcn_mfma_f32_16x16x32_bf16(ah0, bh1, acc01, 0, 0, 0);
      acc01 = __builtin_amdgcn_mfma_f32_16x16x32_bf16(ah0, bl1, acc01, 0, 0, 0);
      acc01 = __builtin_amdgcn_mfma_f32_16x16x32_bf16(al0, bh1, acc01, 0, 0, 0);
      acc10 = __builtin_amdgcn_mfma_f32_16x16x32_bf16(ah1, bh0, acc10, 0, 0, 0);
      acc10 = __builtin_amdgcn_mfma_f32_16x16x32_bf16(ah1, bl0, acc10, 0, 0, 0);
      acc10 = __builtin_amdgcn_mfma_f32_16x16x32_bf16(al1, bh0, acc10, 0, 0, 0);
      acc11 = __builtin_amdgcn_mfma_f32_16x16x32_bf16(ah1, bh1, acc11, 0, 0, 0);
      acc11 = __builtin_amdgcn_mfma_f32_16x16x32_bf16(ah1, bl1, acc11, 0, 0, 0);
      acc11 = __builtin_amdgcn_mfma_f32_16x16x32_bf16(al1, bh1, acc11, 0, 0, 0);
    }
    __syncthreads();
  }
  #pragma unroll
  for (int r = 0; r < 4; r++) {
    int row0 = bm + wr * 32 + q * 4 + r;
    int row1 = row0 + 16;
    int col0 = bn + wc * 32 + mrow;
    float vv[4] = {acc00[r], acc01[r], acc10[r], acc11[r]};
    int rows[4] = {row0, row0, row1, row1};
    int cols[4] = {col0, col0 + 16, col0, col0 + 16};
    #pragma unroll
    for (int e = 0; e < 4; e++) {
      Y[(size_t)rows[e] * DD + cols[e]] = vv[e];
      unsigned short h = f2bf(vv[e]), l = f2bf(vv[e] - bf2f(h));
      Pm[(size_t)rows[e] * 1024 + cols[e]] = h;
      Pm[(size_t)rows[e] * 1024 + 512 + cols[e]] = l;
    }
  }
}

// ---- wm rows: wm[row] = W[row, 0..row] . m (4 rows per block) ----
__device__ __forceinline__ void wm_rows(const float* __restrict__ W,
    const float* __restrict__ m, float* __restrict__ wm, int r0) {
  int tid = threadIdx.x;
  int wave = tid >> 6, lane = tid & 63;
  int row = r0 + wave;
  float s = 0.0f;
  for (int j = lane; j <= row; j += 64) s += W[(size_t)row * DD + j] * m[j];
  for (int off = 32; off > 0; off >>= 1) s += __shfl_down(s, off);
  if (lane == 0) wm[row] = s;
}

// ============ F1: diag-inv(+PW), consts, mu/mun/rowmap(+PX), px rows 0..1023 ============
__global__ __launch_bounds__(256) void f_init(const float* tdiag, const float* tlow,
    const float* kappa, const float* nu, const int* labels, const float* Xs,
    const float* Xq, const float* m, float* W, float* cst,
    int* rowmap, float* mu, float* mun,
    unsigned short* PX, unsigned short* PW) {
  __shared__ float sh[2 * 64 * 68 + 32 * 33];   // Ld | Wd | tsh = 39 KB
  __shared__ int sidx[SHOTS];
  int b = blockIdx.x, tid = threadIdx.x;
  if (b < 8) {
    // diag 64x64 inverse via blocked 16->32->64 (critical path: dispatch first)
    int jb = b;
    float* Ld = sh;                   // [64][68]
    float* Wd = sh + 64 * 68;         // [64][68]
    float* tsh = sh + 2 * 64 * 68;    // [32][33]
    for (int t = tid; t < 4096; t += 256) {
      int r = t >> 6, c = t & 63;
      int gr = jb * 64 + r;
      float v = (r == c) ? fabsf(tdiag[gr])
              : (r > c ? tlow[(size_t)gr * DD + jb * 64 + c] : 0.0f);
      Ld[r * 68 + c] = v;
      Wd[r * 68 + c] = 0.0f;
    }
    __syncthreads();
    if (tid < 64) {
      // 16x16 base inverse, column t of sub-block s — register chain
      int s = tid >> 4, t = tid & 15;
      int r0 = s * 16;
      float wreg[16];
      #pragma unroll
      for (int i = 0; i < 16; i++) {
        float w = (i == t) ? 1.0f : 0.0f;
        #pragma unroll
        for (int k = 0; k < 16; k++)
          if (k < i) w -= Ld[(r0 + i) * 68 + r0 + k] * wreg[k];
        wreg[i] = w / Ld[(r0 + i) * 68 + r0 + i];
      }
      #pragma unroll
      for (int i = 0; i < 16; i++) Wd[(r0 + i) * 68 + r0 + t] = wreg[i];
    }
    __syncthreads();
    for (int g2 = 0; g2 < 2; g2++) {
      int r0 = g2 * 32 + 16, c0 = g2 * 32;
      int rr = tid >> 4, cc = tid & 15;
      float t_ = 0.0f;
      #pragma unroll
      for (int k = 0; k < 16; k++)
        t_ += Ld[(r0 + rr) * 68 + c0 + k] * Wd[(c0 + k) * 68 + c0 + cc];
      tsh[rr * 33 + cc] = t_;
      __syncthreads();
      float x = 0.0f;
      #pragma unroll
      for (int k = 0; k < 16; k++)
        x -= Wd[(r0 + rr) * 68 + r0 + k] * tsh[k * 33 + cc];
      Wd[(r0 + rr) * 68 + c0 + cc] = x;
      __syncthreads();
    }
    {
      int rr = tid >> 6, cc = tid & 63;
      #pragma unroll
      for (int p = 0; p < 4; p++) {
        int r = rr + p * 4, c = cc;
        if (c < 32) {
          float t_ = 0.0f;
          #pragma unroll
          for (int k = 0; k < 32; k++)
            t_ += Ld[(32 + r) * 68 + k] * Wd[k * 68 + c];
          tsh[r * 33 + c] = t_;
        } else {
          int c2 = c - 32;
          float t_ = 0.0f;
          #pragma unroll
          for (int k = 0; k < 32; k++)
            t_ += Ld[(32 + r + 16) * 68 + k] * Wd[k * 68 + c2];
          tsh[(r + 16) * 33 + c2] = t_;
        }
      }
      __syncthreads();
      #pragma unroll
      for (int p = 0; p < 4; p++) {
        int r = rr + p * 4, c = cc;
        int r2 = (c < 32) ? r : r + 16;
        int c2 = (c < 32) ? c : c - 32;
        float x = 0.0f;
        #pragma unroll
        for (int k = 0; k < 32; k++)
          x -= Wd[(32 + r2) * 68 + 32 + k] * tsh[k * 33 + c2];
        Wd[(32 + r2) * 68 + c2] = x;
      }
    }
    __syncthreads();
    float* Wblk = W + (size_t)(jb * 64) * DD + jb * 64;
    for (int t = tid; t < 4096; t += 256) {
      int r = t >> 6, c = t & 63;
      float v = Wd[r * 68 + c];
      Wblk[(size_t)r * DD + c] = v;
      unsigned short h = f2bf(v), l = f2bf(v - bf2f(h));
      size_t prow = (size_t)(jb * 64 + r) * 1024 + jb * 64 + c;
      PW[prow] = h;
      PW[prow + 512] = l;
    }
  } else if (b == 8) {
    if (tid == 0) {
      float kap = fabsf(kappa[0]) + 1e-6f;
      float nu_ = fmaxf(nu[0], (float)(DD - 1) + 1e-6f);
      float common = nu_ + (float)SHOTS + 1.0f - (float)DD;
      float scale = (kap + SHOTS + 1.0f) / ((nu_ + SHOTS - DD + 1.0f) * (kap + SHOTS));
      cst[0] = kap;
      cst[1] = scale;
      cst[2] = common;
      cst[3] = 0.5f * (common + DD);
      cst[4] = lgammaf(0.5f * (common + DD)) - lgammaf(0.5f * common)
               - 0.5f * (float)DD * logf(common);
      cst[5] = -(kap + SHOTS);
      cst[6] = kap / (kap + SHOTS);
      cst[7] = 1.0f / (kap + SHOTS);
      cst[8] = (float)DD * logf(scale);
      cst[9] = -1.0f / (kap + SHOTS);
    }
  } else if (b < 73) {
    // mu/mun/rowmap with locally derived idx; also emit PX for mu rows
    int c = b - 9;
    if (tid < 64) {
      int lane = tid, cnt = 0;
      for (int i0 = 0; i0 < NSUP; i0 += 64) {
        int lab = labels[i0 + lane];
        unsigned long long mm = __ballot(lab == c);
        if (lab == c) {
          int pos = cnt + __popcll(mm & ((1ull << lane) - 1ull));
          if (pos < SHOTS) sidx[pos] = i0 + lane;
        }
        cnt += __popcll(mm);
      }
    }
    __syncthreads();
    if (tid < 17)
      rowmap[c * 17 + tid] = (tid < SHOTS) ? (QNQ + sidx[tid]) : (QNQ + NSUP + c);
    float kap = fabsf(kappa[0]) + 1e-6f;
    float cm = kap / (kap + SHOTS), cx = 1.0f / (kap + SHOTS);
    float* red = sh;
    float acc = 0.0f;
    size_t prow = (size_t)(3072 + c) * 1024;
    for (int d = tid; d < DD; d += 256) {
      float s = 0.0f;
      for (int sh_ = 0; sh_ < SHOTS; sh_++)
        s += Xs[(size_t)sidx[sh_] * DD + d];
      float v = cm * m[d] + cx * s;
      mu[(size_t)c * DD + d] = v;
      unsigned short h = f2bf(v), l = f2bf(v - bf2f(h));
      PX[prow + d] = h;
      PX[prow + 512 + d] = l;
      acc += v * v;
    }
    red[tid] = acc;
    __syncthreads();
    for (int off = 128; off > 0; off >>= 1) {
      if (tid < off) red[tid] += red[tid + off];
      __syncthreads();
    }
    if (tid == 0) mun[c] = red[0];
  } else {
    px_rows(Xq, Xs, PX, (b - 73) * 4);        // rows 0..1023
  }
}

// ---- 64x64 tile helpers (stride-68 LDS) ----
__device__ __forceinline__ void tile_stage(float* S, const float* __restrict__ G, int ldg) {
  int tid = threadIdx.x;
  #pragma unroll
  for (int p = 0; p < 4; p++) {
    int f4 = tid + 256 * p;
    int row = f4 >> 4, c4 = (f4 & 15) * 4;
    *(float4*)&S[row * 68 + c4] = *(const float4*)(G + (size_t)row * ldg + c4);
  }
}
__device__ __forceinline__ void tile_fma(float acc[4][4], const float* As, const float* Bs) {
  int tid = threadIdx.x, tr = tid >> 4, tc = tid & 15;
  #pragma unroll
  for (int kk = 0; kk < 64; kk++) {
    float a[4];
    #pragma unroll
    for (int x = 0; x < 4; x++) a[x] = As[(tr * 4 + x) * 68 + kk];
    float4 bv = *(const float4*)&Bs[kk * 68 + tc * 4];
    float bb[4] = {bv.x, bv.y, bv.z, bv.w};
    #pragma unroll
    for (int x = 0; x < 4; x++)
      #pragma unroll
      for (int y = 0; y < 4; y++) acc[x][y] += a[x] * bb[y];
  }
}
__device__ __forceinline__ void tile_out_neg(const float acc[4][4], float* W,
    unsigned short* PW, int gr0, int gc0) {
  int tid = threadIdx.x, tr = tid >> 4, tc = tid & 15;
  #pragma unroll
  for (int x = 0; x < 4; x++) {
    #pragma unroll
    for (int y = 0; y < 4; y++) {
      float v = -acc[x][y];
      W[(size_t)(gr0 + tr * 4 + x) * DD + gc0 + tc * 4 + y] = v;
      unsigned short h = f2bf(v), l = f2bf(v - bf2f(h));
      size_t prow = (size_t)(gr0 + tr * 4 + x) * 1024 + gc0 + tc * 4 + y;
      PW[prow] = h;
      PW[prow + 512] = l;
    }
  }
}

#define GBK 32
// ============ merged trinv level 128 + xmu partials + px rows 1024..2047 ============
__global__ __launch_bounds__(256) void k_m128_xmu(const float* __restrict__ tlow,
    const float* __restrict__ W_, float* __restrict__ Wout,
    const float* __restrict__ Xq, const float* __restrict__ Mu,
    float* __restrict__ xmup, unsigned short* __restrict__ PW,
    const float* __restrict__ Xs, unsigned short* __restrict__ PX) {
  __shared__ float sh[3 * 64 * 68];   // As | Bs | tsh = 52.2 KB
  int b = blockIdx.x, tid = threadIdx.x;
  if (b < 4) {
    float* As = sh;
    float* Bs = sh + 64 * 68;
    float* tsh = sh + 2 * 64 * 68;
    int base = b * 128;
    float tacc[4][4] = {};
    tile_stage(As, tlow + (size_t)(base + 64) * DD + base, DD);   // C
    tile_stage(Bs, W_ + (size_t)base * DD + base, DD);            // Ainv
    __syncthreads();
    tile_fma(tacc, As, Bs);
    __syncthreads();
    {
      int tr = tid >> 4, tc = tid & 15;
      #pragma unroll
      for (int x = 0; x < 4; x++)
        #pragma unroll
        for (int y = 0; y < 4; y++) tsh[(tr * 4 + x) * 68 + tc * 4 + y] = tacc[x][y];
    }
    tile_stage(As, W_ + (size_t)(base + 64) * DD + base + 64, DD); // Binv
    __syncthreads();
    float xacc[4][4] = {};
    tile_fma(xacc, As, tsh);
    tile_out_neg(xacc, Wout, PW, base + 64, base);
  } else if (b < 260) {     // xmu partials transposed: 32 q-cols x 64 c-rows
    float* Ms = sh;               // Mu: GBK k-rows x 64, stride 68
    float* Qs = sh + 64 * 68;     // Xq: GBK k-rows x 32, stride 36
    int xb = b - 4;
    int bm = (xb & 63) * 32, kq = xb >> 6;
    int tr = tid >> 4, tc = tid & 15;   // tr: c-group of 4, tc: q-pair
    float acc[4][2] = {};
    int k0s = kq * (DD / XKS), k0e = k0s + DD / XKS;
    for (int k0 = k0s; k0 < k0e; k0 += GBK) {
      #pragma unroll
      for (int p = 0; p < 2; p++) {
        int idx = tid + 256 * p;            // Mu 64x32 = 512 float4
        int row = idx >> 3, k4 = idx & 7;
        float4 v = *(const float4*)(Mu + (size_t)row * DD + k0 + k4 * 4);
        Ms[(k4 * 4 + 0) * 68 + row] = v.x; Ms[(k4 * 4 + 1) * 68 + row] = v.y;
        Ms[(k4 * 4 + 2) * 68 + row] = v.z; Ms[(k4 * 4 + 3) * 68 + row] = v.w;
      }
      {
        int row = tid >> 3, k4 = tid & 7;   // Xq 32x32 = 256 float4
        float4 v = *(const float4*)(Xq + (size_t)(bm + row) * DD + k0 + k4 * 4);
        Qs[(k4 * 4 + 0) * 36 + row] = v.x; Qs[(k4 * 4 + 1) * 36 + row] = v.y;
        Qs[(k4 * 4 + 2) * 36 + row] = v.z; Qs[(k4 * 4 + 3) * 36 + row] = v.w;
      }
      __syncthreads();
      #pragma unroll
      for (int kk = 0; kk < GBK; kk++) {
        float4 m0 = *(const float4*)&Ms[kk * 68 + tr * 4];
        float a[4] = {m0.x, m0.y, m0.z, m0.w};
        float q0 = Qs[kk * 36 + tc * 2], q1 = Qs[kk * 36 + tc * 2 + 1];
        #pragma unroll
        for (int y = 0; y < 4; y++) {
          acc[y][0] += a[y] * q0;
          acc[y][1] += a[y] * q1;
        }
      }
      __syncthreads();
    }
    #pragma unroll
    for (int y = 0; y < 4; y++) {
      float2 v = make_float2(acc[y][0], acc[y][1]);
      *(float2*)(xmup + ((size_t)kq * CNUM + tr * 4 + y) * QNQ + bm + tc * 2) = v;
    }
  } else {
    px_rows(Xq, Xs, PX, 1024 + (b - 260) * 4);   // rows 1024..2047
  }
}

// ============ merged trinv level 256 (+px rows 2048..3071) ============
__global__ __launch_bounds__(256) void k_m256(const float* __restrict__ tlow,
    float* __restrict__ W, unsigned short* __restrict__ PW,
    const float* __restrict__ Xq, const float* __restrict__ Xs,
    unsigned short* __restrict__ PX) {
  __shared__ float sh[3 * 64 * 68];
  int b = blockIdx.x, tid = threadIdx.x;
  if (b >= 8) { px_rows(Xq, Xs, PX, 2048 + (b - 8) * 4); return; }
  float* As = sh;
  float* Bs = sh + 64 * 68;
  float* tsh = sh + 2 * 64 * 68;
  int g = b >> 2, rem = b & 3, i = rem >> 1, j = rem & 1;
  int base = g * 256;
  float xacc[4][4] = {};
  for (int k = 0; k <= i; k++) {
    float tacc[4][4] = {};
    for (int l = j; l < 2; l++) {
      __syncthreads();
      tile_stage(As, tlow + (size_t)(base + 128 + 64 * k) * DD + base + 64 * l, DD); // C(k,l)
      tile_stage(Bs, W + (size_t)(base + 64 * l) * DD + base + 64 * j, DD);          // Ainv(l,j)
      __syncthreads();
      tile_fma(tacc, As, Bs);
    }
    __syncthreads();
    {
      int tr = tid >> 4, tc = tid & 15;
      #pragma unroll
      for (int x = 0; x < 4; x++)
        #pragma unroll
        for (int y = 0; y < 4; y++) tsh[(tr * 4 + x) * 68 + tc * 4 + y] = tacc[x][y];
    }
    tile_stage(As, W + (size_t)(base + 128 + 64 * i) * DD + base + 128 + 64 * k, DD); // Binv(i,k)
    __syncthreads();
    tile_fma(xacc, As, tsh);
  }
  tile_out_neg(xacc, W, PW, base + 128 + 64 * i, base + 64 * j);
}

// 64x64 NN GEMM tile on caller LDS (stride 68)
__device__ __forceinline__ void nn64_sh(float* As, float* Bs,
    const float* __restrict__ A, int lda, const float* __restrict__ B, int ldb,
    float* __restrict__ Cd, int ldc, int k0, int k1, float sgn,
    unsigned short* __restrict__ Pw, int gr0, int gc0) {
  int tid = threadIdx.x, tr = tid >> 4, tc = tid & 15;
  float acc[4][4] = {};
  for (int kc = k0; kc < k1; kc += 64) {
    #pragma unroll
    for (int p = 0; p < 4; p++) {
      int f4 = tid + 256 * p;
      int row = f4 >> 4, c4 = f4 & 15;
      *(float4*)&As[row * 68 + c4 * 4] = *(const float4*)(A + (size_t)row * lda + kc + c4 * 4);
      *(float4*)&Bs[row * 68 + c4 * 4] = *(const float4*)(B + (size_t)(kc + row) * ldb + c4 * 4);
    }
    __syncthreads();
    #pragma unroll
    for (int kk = 0; kk < 64; kk++) {
      float a[4];
      #pragma unroll
      for (int x = 0; x < 4; x++) a[x] = As[(tr * 4 + x) * 68 + kk];
      float4 bv = *(const float4*)&Bs[kk * 68 + tc * 4];
      float bb[4] = {bv.x, bv.y, bv.z, bv.w};
      #pragma unroll
      for (int x = 0; x < 4; x++)
        #pragma unroll
        for (int y = 0; y < 4; y++) acc[x][y] += a[x] * bb[y];
    }
    __syncthreads();
  }
  #pragma unroll
  for (int x = 0; x < 4; x++) {
    float4 v = make_float4(sgn * acc[x][0], sgn * acc[x][1],
                           sgn * acc[x][2], sgn * acc[x][3]);
    *(float4*)(Cd + (size_t)(tr * 4 + x) * ldc + tc * 4) = v;
    if (Pw) {
      size_t prow = (size_t)(gr0 + tr * 4 + x) * 1024 + gc0 + tc * 4;
      float vv[4] = {v.x, v.y, v.z, v.w};
      #pragma unroll
      for (int y = 0; y < 4; y++) {
        unsigned short h = f2bf(vv[y]), l = f2bf(vv[y] - bf2f(h));
        Pw[prow + y] = h;
        Pw[prow + 512 + y] = l;
      }
    }
  }
}

// ============ trinv level-512 T + Y-tiles nt<4 + wm rows<256 ============
__global__ __launch_bounds__(256) void k_triT(const float* __restrict__ tlow,
    const float* __restrict__ W, float* __restrict__ T,
    const unsigned short* __restrict__ PX, const unsigned short* __restrict__ PW,
    const float* __restrict__ m, float* __restrict__ Y,
    unsigned short* __restrict__ Pm, float* __restrict__ wm) {
  __shared__ unsigned short ush[4 * 64 * PSTR];   // 36.9 KB (fits nn64's 34.8 KB too)
  int b = blockIdx.x;
  if (b < 16) {
    int ti = b >> 2, tj = b & 3;
    const float* A = tlow + (size_t)(256 + ti * 64) * DD;
    const float* B = W + (size_t)tj * 64;
    float* Cd = T + (size_t)(ti * 64) * 256 + tj * 64;
    nn64_sh((float*)ush, (float*)ush + 64 * 68, A, DD, B, DD, Cd, 256,
            tj * 64, 256, 1.0f, nullptr, 0, 0);
  } else if (b < 212) {     // 196 Y-tiles, nt<4
    int t = b - 16;
    y_tile(PX, PW, Y, Pm, ush, t >> 2, t & 3);
  } else {                  // wm rows 0..255
    wm_rows(W, m, wm, (b - 212) * 4);
  }
}

// ============ trinv level-512 X (emits PW) ============
__global__ __launch_bounds__(256) void k_triX(float* __restrict__ W,
                                              const float* __restrict__ T,
                                              unsigned short* __restrict__ PW) {
  __shared__ float sh[2 * 64 * 68];
  int b = blockIdx.x;
  int ti = b >> 2, tj = b & 3;
  const float* A = W + (size_t)(256 + ti * 64) * DD + 256;
  const float* B = T + tj * 64;
  int gr0 = 256 + ti * 64, gc0 = tj * 64;
  float* Cd = W + (size_t)gr0 * DD + gc0;
  nn64_sh(sh, sh + 64 * 68, A, DD, B, 256, Cd, DD, 0, (ti + 1) * 64, -1.0f, PW, gr0, gc0);
}

// ============ F3: remaining Y-tiles (nt>=4, need full W) + wm rows>=256 ============
__global__ __launch_bounds__(256) void f_y_wm(const unsigned short* __restrict__ PX,
    const unsigned short* __restrict__ PW, const float* __restrict__ W,
    const float* __restrict__ m, float* __restrict__ Y,
    unsigned short* __restrict__ Pm, float* __restrict__ wm) {
  __shared__ unsigned short ush[4 * 64 * PSTR];
  int b = blockIdx.x;
  if (b < 196) {
    y_tile(PX, PW, Y, Pm, ush, b >> 2, 4 + (b & 3));
  } else {                  // wm rows 256..511
    wm_rows(W, m, wm, 256 + (b - 196) * 4);
  }
}

// ============ F5: gram-first + Rg 4-buf 8-iter 3-combo + query rows (8/block) ============
// grid 865 <= 1024 residency (4 blocks/CU at 36.9 KB LDS): no straggler wave.
__global__ __launch_bounds__(256) void f_z_rg_gram(const unsigned short* __restrict__ Pm,
    const float* __restrict__ Y, const float* __restrict__ tdiag,
    const int* __restrict__ rowmap, const float* __restrict__ Xq,
    const float* __restrict__ wm, float* __restrict__ cst,
    float* __restrict__ Rg,
    float* __restrict__ z, float* __restrict__ qn, float* __restrict__ yn,
    float* __restrict__ zg, float* __restrict__ Vmu, float* __restrict__ muBmu,
    float* __restrict__ Minv, float* __restrict__ bias) {
  __shared__ float sh[9216];   // 36.9 KB: 4x64xPSTR bf16 staging | gram arrays (9095 f)
  __shared__ float csmS;
  int b = blockIdx.x, tid = threadIdx.x;
  if (b < 64) {               // gram + register-GJ inverse + bias, one class per block
    int c = b;
    int lane = tid & 63, wave = tid >> 6;
    float* Ys  = sh;                 // 17 x 516
    float* aug = sh + 8772;          // 17 x 18 (left half only; identity in regs)
    float* zsv = aug + 306;          // 17
    float kap = cst[0], cst9 = cst[9];
    for (int t = tid; t < 17 * 128; t += 256) {
      int r = t >> 7, col = t & 127;
      *(float4*)&Ys[r * 516 + col * 4] =
          *(const float4*)(Y + (size_t)rowmap[c * 17 + r] * DD + col * 4);
    }
    float ldb_r = 0.0f;
    if (wave == 0) {
      float aa = 0.0f, ll = 0.0f;
      for (int t = lane; t < DD; t += 64) {
        float w = wm[t]; aa += w * w;
        ll += logf(fabsf(tdiag[t]));
      }
      #pragma unroll
      for (int off = 32; off > 0; off >>= 1) {
        aa += __shfl_xor(aa, off);
        ll += __shfl_xor(ll, off);
      }
      ldb_r = 2.0f * ll + logf(1.0f + kap * aa);
      if (lane == 0) csmS = kap / (1.0f + kap * aa);
    }
    __syncthreads();          // Ys + csmS ready
    if (wave > 0) {
      for (int a = wave - 1; a < 17; a += 3) {
        float s = 0.0f;
        for (int j = lane; j < 128; j += 64) {
          float4 yv = *(const float4*)&Ys[a * 516 + j * 4];
          float4 wv = *(const float4*)(wm + j * 4);
          s += yv.x * wv.x + yv.y * wv.y + yv.z * wv.z + yv.w * wv.w;
        }
        #pragma unroll
        for (int off = 32; off > 0; off >>= 1) s += __shfl_xor(s, off);
        if (lane == 0) zsv[a] = s;
      }
    }
    __syncthreads();          // zs ready
    float csm = csmS;
    for (int e = tid; e < 153; e += 256) {
      int a = (int)((sqrtf(8.0f * (float)e + 1.0f) - 1.0f) * 0.5f);
      while (((a + 1) * (a + 2)) / 2 <= e) a++;
      while ((a * (a + 1)) / 2 > e) a--;
      int bb = e - (a * (a + 1)) / 2;   // bb <= a
      const float* ra = &Ys[a * 516];
      const float* rb = &Ys[bb * 516];
      float s = 0.0f;
      for (int k = 0; k < 128; k++) {
        float4 va = *(const float4*)&ra[k * 4];
        float4 vb = *(const float4*)&rb[k * 4];
        s += va.x * vb.x + va.y * vb.y + va.z * vb.z + va.w * vb.w;
      }
      float g = s - csm * zsv[a] * zsv[bb];
      if (a == bb) g += (a < 16) ? 1.0f : cst9;
      aug[a * 18 + bb] = g;
      if (a != bb) aug[bb * 18 + a] = g;
    }
    __syncthreads();          // aug ready (LDS copy stays pristine below)
    if (wave == 0) {
      float colv[17];
      bool left = lane < 17;
      bool right = (lane >= 17 && lane < 34);
      #pragma unroll
      for (int r = 0; r < 17; r++) {
        float lv = aug[r * 18 + (lane & 31)];
        colv[r] = left ? lv : ((right && (lane - 17) == r) ? 1.0f : 0.0f);
      }
      float det = 0.0f;
      #pragma unroll
      for (int k = 0; k < 17; k++) {
        float best = fabsf(colv[k]); int bp = k;
        #pragma unroll
        for (int r = k + 1; r < 17; r++) {
          float v = fabsf(colv[r]);
          if (v > best) { best = v; bp = r; }
        }
        int p = __shfl(bp, k);
        float pv = colv[k];
        #pragma unroll
        for (int r = k + 1; r < 17; r++) pv = (p == r) ? colv[r] : pv;
        float oldk = colv[k];
        #pragma unroll
        for (int r = k + 1; r < 17; r++) colv[r] = (p == r) ? oldk : colv[r];
        colv[k] = pv;
        float piv = __shfl(pv, k);
        if (lane == 0) det += logf(fabsf(piv));
        float invp = 1.0f / piv;
        float rk = pv * invp;
        colv[k] = rk;
        #pragma unroll
        for (int r = 0; r < 17; r++) {
          if (r == k) continue;
          float ck = __shfl(colv[r], k);
          colv[r] = fmaf(-ck, rk, colv[r]);
        }
      }
      if (right) {
        int bb = lane - 17;
        #pragma unroll
        for (int r = 0; r < 17; r++)
          Minv[(size_t)c * 289 + r * 17 + bb] = colv[r];
      }
      if (lane == 0) {
        float slog = logf(fabsf(cst[5])) + det;
        float logdetSigma = cst[8] + ldb_r + slog;
        bias[c] = cst[4] - 0.5f * logdetSigma;
      }
    } else if (wave == 1) {   // concurrent with wave 0's GJ
      if (lane < 17) {
        float gv = aug[lane * 18 + 16];
        if (lane == 16) gv -= cst9;
        Vmu[c * 17 + lane] = gv;
        if (lane == 16) muBmu[c] = gv;
        zg[c * 17 + lane] = zsv[lane];
      }
    }
  } else if (b == 64) {       // SM consts for k_logits (identical arithmetic)
    if (tid < 64) {
      float aa = 0.0f, ll = 0.0f;
      for (int t = tid; t < DD; t += 64) {
        float w = wm[t]; aa += w * w;
        ll += logf(fabsf(tdiag[t]));
      }
      #pragma unroll
      for (int off = 32; off > 0; off >>= 1) {
        aa += __shfl_xor(aa, off);
        ll += __shfl_xor(ll, off);
      }
      if (tid == 0) {
        float kap = cst[0];
        cst[10] = kap / (1.0f + kap * aa);
        cst[11] = 2.0f * ll + logf(1.0f + kap * aa);
      }
    }
  } else if (b < 609) {       // Rg: 17x32 64x64 tiles; 4-buf 8-iter, lo*lo dropped
    unsigned short* ush = (unsigned short*)sh;
    unsigned short* AH = ush;
    unsigned short* AL = ush + 64 * PSTR;
    unsigned short* BH = ush + 2 * 64 * PSTR;
    unsigned short* BL = ush + 3 * 64 * PSTR;
    int rb = b - 65;
    int bm = (rb >> 5) * 64, bn = (rb & 31) * 64;
    int lane = tid & 63, wave = tid >> 6;
    int wr = wave >> 1, wc = wave & 1;
    int mrow = lane & 15, q = lane >> 4;
    int srowA[2];
    #pragma unroll
    for (int p = 0; p < 2; p++) srowA[p] = rowmap[bm + ((tid + 256 * p) >> 3)];
    f32x4 acc00 = {}, acc01 = {}, acc10 = {}, acc11 = {};
    for (int it = 0; it < 8; it++) {
      int kc = it * 64;
      #pragma unroll
      for (int p = 0; p < 2; p++) {
        int idx = tid + 256 * p;
        int row = idx >> 3, c8 = (idx & 7) * 8;
        *(short8*)&AH[row * PSTR + c8] =
            *(const short8*)(Pm + (size_t)srowA[p] * 1024 + kc + c8);
        *(short8*)&AL[row * PSTR + c8] =
            *(const short8*)(Pm + (size_t)srowA[p] * 1024 + 512 + kc + c8);
        *(short8*)&BH[row * PSTR + c8] =
            *(const short8*)(Pm + (size_t)(bn + row) * 1024 + kc + c8);
        *(short8*)&BL[row * PSTR + c8] =
            *(const short8*)(Pm + (size_t)(bn + row) * 1024 + 512 + kc + c8);
      }
      __syncthreads();
      #pragma unroll
      for (int ks = 0; ks < 2; ks++) {
        int ko = ks * 32 + q * 8;
        short8 ah0 = *(const short8*)&AH[(wr * 32 + mrow) * PSTR + ko];
        short8 ah1 = *(const short8*)&AH[(wr * 32 + 16 + mrow) * PSTR + ko];
        short8 al0 = *(const short8*)&AL[(wr * 32 + mrow) * PSTR + ko];
        short8 al1 = *(const short8*)&AL[(wr * 32 + 16 + mrow) * PSTR + ko];
        short8 bh0 = *(const short8*)&BH[(wc * 32 + mrow) * PSTR + ko];
        short8 bh1 = *(const short8*)&BH[(wc * 32 + 16 + mrow) * PSTR + ko];
        short8 bl0 = *(const short8*)&BL[(wc * 32 + mrow) * PSTR + ko];
        short8 bl1 = *(const short8*)&BL[(wc * 32 + 16 + mrow) * PSTR + ko];
        acc00 = __builtin_amdgcn_mfma_f32_16x16x32_bf16(ah0, bh0, acc00, 0, 0, 0);
        acc00 = __builtin_amdgcn_mfma_f32_16x16x32_bf16(ah0, bl0, acc00, 0, 0, 0);
        acc00 = __builtin_amdgcn_mfma_f32_16x16x32_bf16(al0, bh0, acc00, 0, 0, 0);
        acc01 = __builtin_amdgcn_mfma_f32_16x16x32_bf16(ah0, bh1, acc01, 0, 0, 0);
        acc01 = __builtin_amdgcn_mfma_f32_16x16x32_bf16(ah0, bl1, acc01, 0, 0, 0);
        acc01 = __builtin_amdgcn_mfma_f32_16x16x32_bf16(al0, bh1, acc01, 0, 0, 0);
        acc10 = __builtin_amdgcn_mfma_f32_16x16x32_bf16(ah1, bh0, acc10, 0, 0, 0);
        acc10 = __builtin_amdgcn_mfma_f32_16x16x32_bf16(ah1, bl0, acc10, 0, 0, 0);
        acc10 = __builtin_amdgcn_mfma_f32_16x16x32_bf16(al1, bh0, acc10, 0, 0, 0);
        acc11 = __builtin_amdgcn_mfma_f32_16x16x32_bf16(ah1, bh1, acc11, 0, 0, 0);
        acc11 = __builtin_amdgcn_mfma_f32_16x16x32_bf16(ah1, bl1, acc11, 0, 0, 0);
        acc11 = __builtin_amdgcn_mfma_f32_16x16x32_bf16(al1, bh1, acc11, 0, 0, 0);
      }
      __syncthreads();
    }
    #pragma unroll
    for (int r = 0; r < 4; r++) {
      int row0 = bm + wr * 32 + q * 4 + r;
      int row1 = row0 + 16;
      int col0 = bn + wc * 32 + mrow;
      Rg[(size_t)row0 * QNQ + col0]      = acc00[r];
      Rg[(size_t)row0 * QNQ + col0 + 16] = acc01[r];
      Rg[(size_t)row1 * QNQ + col0]      = acc10[r];
      Rg[(size_t)row1 * QNQ + col0 + 16] = acc11[r];
    }
  } else {                    // query rows (8 per block): z = Y.wm, qn, yn
    int wave = tid >> 6, lane = tid & 63;
    int base = (b - 609) * 8;
    #pragma unroll
    for (int rr = 0; rr < 2; rr++) {
      int row = base + rr * 4 + wave;
      const float* xr = Xq + (size_t)row * DD;
      const float* yr = Y + (size_t)row * DD;
      float sz = 0.0f, s1 = 0.0f, s2 = 0.0f;
      for (int j4 = lane; j4 < 128; j4 += 64) {
        float4 xv = *(const float4*)(xr + j4 * 4);
        float4 yv = *(const float4*)(yr + j4 * 4);
        float4 wv = *(const float4*)(wm + j4 * 4);
        sz += yv.x * wv.x + yv.y * wv.y + yv.z * wv.z + yv.w * wv.w;
        s1 += xv.x * xv.x + xv.y * xv.y + xv.z * xv.z + xv.w * xv.w;
        s2 += yv.x * yv.x + yv.y * yv.y + yv.z * yv.z + yv.w * yv.w;
      }
      for (int off = 32; off > 0; off >>= 1) {
        sz += __shfl_down(sz, off);
        s1 += __shfl_down(s1, off);
        s2 += __shfl_down(s2, off);
      }
      if (lane == 0) {
        z[row] = sz;
        qn[row] = s1;
        yn[row] = s2;
      }
    }
  }
}

// final epilogue: Woodbury-corrected Mahalanobis -> logits[q,c]
__global__ __launch_bounds__(256) void k_logits(const float* __restrict__ Rg,
    const float* z, const float* zg,
    const float* Vmu, const float* muBmu, const float* mun, const float* yn,
    const float* qn, const float* xmup, const float* Minv, const float* bias,
    const float* cst, float* out) {
  __shared__ float Ms[289], Vs[17], Zs[17];
  int c = blockIdx.y;
  int q = blockIdx.x * 256 + threadIdx.x;
  for (int t = threadIdx.x; t < 289; t += 256) Ms[t] = Minv[(size_t)c * 289 + t];
  if (threadIdx.x < 17) {
    Vs[threadIdx.x] = Vmu[c * 17 + threadIdx.x];
    Zs[threadIdx.x] = zg[c * 17 + threadIdx.x];
  }
  __syncthreads();
  float csm = cst[10], scale = cst[1], common = cst[2], coef = cst[3];
  float zq = z[q];
  float r[17];
  float xBmu = 0.0f;
  for (int a = 0; a < 17; a++) {
    float raw = Rg[(size_t)(c * 17 + a) * QNQ + q] - csm * Zs[a] * zq;
    if (a == 16) xBmu = raw;
    r[a] = raw - Vs[a];
  }
  float qB = yn[q] - csm * zq * zq;
  float quadB = qB - 2.0f * xBmu + muBmu[c];
  float corr = 0.0f;
  for (int a = 0; a < 17; a++) {
    float e = 0.0f;
    for (int bb = 0; bb < 17; bb++) e += Ms[a * 17 + bb] * r[bb];
    corr += r[a] * e;
  }
  float distB = (quadB - corr) / scale;
  float xm = 0.0f;
  #pragma unroll
  for (int p = 0; p < XKS; p++)
    xm += xmup[((size_t)(p * CNUM + c)) * QNQ + q];   // [p][c][q]: coalesced in q
  float dn = qn[q] - 2.0f * xm + mun[c];
  float dist = (1.0f - REGP) * distB + REGP * dn;
  out[(size_t)q * CNUM + c] = bias[c] - coef * log1pf(dist / common);
}

// ---------------- host ----------------
extern "C" void kernel_launch(void* const* d_in, const int* in_sizes, int n_in,
                              void* d_out, int out_size, void* d_ws, size_t ws_size,
                              hipStream_t stream) {
  const float* Xs    = (const float*)d_in[0];
  const int*   labels= (const int*)d_in[1];
  const float* Xq    = (const float*)d_in[2];
  const float* m     = (const float*)d_in[3];
  const float* kappa = (const float*)d_in[4];
  const float* nu    = (const float*)d_in[5];
  const float* tdiag = (const float*)d_in[6];
  const float* tlow  = (const float*)d_in[7];
  float* ws = (float*)d_ws;
  float* W    = ws + OFF_W;
  float* mu   = ws + OFF_MU;
  float* Y    = ws + OFF_Y;
  float* z    = ws + OFF_Z;
  float* wm   = ws + OFF_WM;
  float* cst  = ws + OFF_CONST;
  int*   rmap = (int*)(ws + OFF_RMAP);
  float* zg   = ws + OFF_ZG;
  float* Vmu  = ws + OFF_VMU;
  float* muBmu= ws + OFF_MUBMU;
  float* mun  = ws + OFF_MUN;
  float* Minv = ws + OFF_MINV;
  float* bias = ws + OFF_BIAS;
  float* qn   = ws + OFF_QNRM;
  float* yn   = ws + OFF_YN;
  float* xmup = ws + OFF_XMU;
  float* Rg   = ws + OFF_RG;
  unsigned short* P  = (unsigned short*)(ws + OFF_P);
  unsigned short* PX = (unsigned short*)(ws + OFF_PX);
  unsigned short* PW = (unsigned short*)(ws + OFF_PW);
  float* Ttmp = ws + OFF_RG;       // trinv scratch, reused (Rg written later)
  float* out  = (float*)d_out;

  // F1: diag-inv(+PW) + consts + mu/mun/rowmap(+PX) + px rows 0..1023
  f_init<<<73 + 256, 256, 0, stream>>>(tdiag, tlow, kappa, nu, labels, Xs, Xq, m,
                                       W, cst, rmap, mu, mun, PX, PW);
  // m128 trinv + xmu + px rows 1024..2047
  k_m128_xmu<<<260 + 256, 256, 0, stream>>>(tlow, W, W, Xq, mu, xmup, PW, Xs, PX);
  // m256 trinv + px rows 2048..3071 (PX complete after this launch)
  k_m256<<<8 + 256, 256, 0, stream>>>(tlow, W, PW, Xq, Xs, PX);
  // triT + early Y-tiles (nt<4, only need W[<256]) + wm rows<256
  k_triT<<<16 + 196 + 64, 256, 0, stream>>>(tlow, W, Ttmp, PX, PW, m, Y, P, wm);
  // triX (completes W/PW)
  k_triX<<<16, 256, 0, stream>>>(W, Ttmp, PW);
  // late Y-tiles (nt>=4) + wm rows>=256
  f_y_wm<<<196 + 64, 256, 0, stream>>>(PX, PW, W, m, Y, P, wm);
  // gram-first + Rg + query rows (8/block): grid 865
  f_z_rg_gram<<<64 + 1 + 544 + 256, 256, 0, stream>>>(P, Y, tdiag, rmap, Xq, wm,
                                                      cst, Rg, z, qn, yn,
                                                      zg, Vmu, muBmu, Minv, bias);
  k_logits<<<dim3(QNQ / 256, CNUM), 256, 0, stream>>>(Rg, z, zg, Vmu, muBmu,
                                                      mun, yn, qn, xmup, Minv, bias,
                                                      cst, out);
  (void)in_sizes; (void)n_in; (void)out_size; (void)ws_size;
}